// Round 4
// baseline (12705.898 us; speedup 1.0000x reference)
//
#include <hip/hip_runtime.h>
#include <cstddef>
#include <cstdint>

#define DIM 128
#define NROUNDS 120
#define NNZ_CAP (1 << 20)
#define NB 250  // persistent grid: 250 blocks, forced 1/CU via LDS footprint (<=256 CUs)
#define IDXCAP 3584  // LDS nz-index pool (ints); per-block avg ~2050, tail ~2600

typedef _Float16 half8 __attribute__((ext_vector_type(8)));
typedef float f32x4 __attribute__((ext_vector_type(4)));
typedef unsigned long long u64;

__device__ __forceinline__ float sigf(float x) { return 1.f / (1.f + __expf(-x)); }
__device__ __forceinline__ float tanh_fast(float x) { return 2.f / (1.f + __expf(-2.f * x)) - 1.f; }

// ---- va WRITES: agent-scope relaxed atomic stores (sc0 sc1 -> write-through to the
// coherence point, no local allocate). va READS: normal cached loads; coherence comes
// from ONE acquire-fence (L1+L2 invalidate) per round -- see persist_kernel loop. ----
__device__ __forceinline__ void st_bypass(_Float16* p, _Float16 v) {
  union { _Float16 f; unsigned short s; } u;
  u.f = v;
  __hip_atomic_store((unsigned short*)p, u.s, __ATOMIC_RELAXED, __HIP_MEMORY_SCOPE_AGENT);
}

// ---------------- sparse build ----------------
__global__ void count_nz_kernel(const float* __restrict__ adj, int* __restrict__ row_cnt,
                                int* __restrict__ col_cnt, int ncols) {
  int i = blockIdx.x;
  int t4 = blockIdx.y * blockDim.x + threadIdx.x;
  int j0 = t4 * 4;
  int c = 0;
  if (j0 < ncols) {
    if ((ncols & 3) == 0) {
      float4 v = *(const float4*)(adj + (size_t)i * ncols + j0);
      if (v.x != 0.f) { atomicAdd(&col_cnt[j0 + 0], 1); ++c; }
      if (v.y != 0.f) { atomicAdd(&col_cnt[j0 + 1], 1); ++c; }
      if (v.z != 0.f) { atomicAdd(&col_cnt[j0 + 2], 1); ++c; }
      if (v.w != 0.f) { atomicAdd(&col_cnt[j0 + 3], 1); ++c; }
    } else {
      for (int e = 0; e < 4 && j0 + e < ncols; ++e)
        if (adj[(size_t)i * ncols + j0 + e] != 0.f) { atomicAdd(&col_cnt[j0 + e], 1); ++c; }
    }
  }
  for (int off = 32; off; off >>= 1) c += __shfl_down(c, off, 64);
  if ((threadIdx.x & 63) == 0 && c) atomicAdd(&row_cnt[i], c);
}

__global__ void scan_kernel(const int* __restrict__ cnt, int* __restrict__ ptr, int n) {
  __shared__ int sdata[256];
  int t = threadIdx.x;
  int per = (n + 255) / 256;
  int beg = t * per;
  int end = beg + per; if (end > n) end = n;
  int local = 0;
  for (int i = beg; i < end; ++i) local += cnt[i];
  sdata[t] = local;
  __syncthreads();
  for (int off = 1; off < 256; off <<= 1) {
    int v = (t >= off) ? sdata[t - off] : 0;
    __syncthreads();
    sdata[t] += v;
    __syncthreads();
  }
  int run = sdata[t] - local;
  for (int i = beg; i < end; ++i) { ptr[i] = run; run += cnt[i]; }
  if (t == 255) ptr[n] = sdata[255];
}

__global__ void copy_int_kernel(const int* __restrict__ a, int* __restrict__ b, int n) {
  int i = blockIdx.x * 256 + threadIdx.x;
  if (i < n) b[i] = a[i];
}

// CSR fill (deterministic order) + CSC fill via atomic column cursors
__global__ __launch_bounds__(64) void fill_csr_csc_kernel(const float* __restrict__ adj,
                                                          const int* __restrict__ row_ptr,
                                                          int* __restrict__ col_idx,
                                                          int* __restrict__ col_cur,
                                                          int* __restrict__ row_idx, int ncols) {
  int row = blockIdx.x;
  int lane = threadIdx.x;
  int base = row_ptr[row];
  int cursor = 0;
  const float* arow = adj + (size_t)row * ncols;
  for (int j0 = 0; j0 < ncols; j0 += 64) {
    int j = j0 + lane;
    bool nz = (j < ncols) && (arow[j] != 0.f);
    u64 m = __ballot(nz);
    int pre = __popcll(m & ((1ull << lane) - 1));
    if (nz) {
      col_idx[base + cursor + pre] = j;
      int t = atomicAdd(&col_cur[j], 1);
      row_idx[t] = row;
    }
    cursor += __popcll(m);
  }
}

// ---------------- weight packing: MFMA 16x16x32 B-fragment order (f16 only) ----------------
__global__ void pack_w_kernel(const float* __restrict__ src, int out_dim,
                              _Float16* __restrict__ dh) {
  int idx = blockIdx.x * 256 + threadIdx.x;
  if (idx >= out_dim * DIM) return;
  int n = idx >> 7, k = idx & 127;
  _Float16 hi = (_Float16)src[idx];
  int nt = n >> 4, ks = k >> 5;
  int L = ((k >> 3) & 3) * 16 + (n & 15);
  int j = k & 7;
  dh[((nt * 4 + ks) * 64 + L) * 8 + j] = hi;
}

__global__ void pack_bias_kernel(const float* __restrict__ a, const float* __restrict__ b,
                                 float* __restrict__ o, int n) {
  int i = blockIdx.x * 256 + threadIdx.x;
  if (i < n) o[i] = a[i] + b[i];
}

// ---------------- LDS swizzle (rows x 128, 8-chunk XOR) ----------------
__device__ __forceinline__ int sw_idx(int m, int k) {
  return (m << 7) + (((((k >> 3) ^ (m & 15))) << 3) | (k & 7));
}

// L2-warm touch: independent line loads covering w[0..n) at 128B stride
__device__ __forceinline__ float touch(const _Float16* __restrict__ w, int n, int tid) {
  float t = 0.f;
  for (int i = tid * 64; i < n; i += 512 * 64) t += (float)w[i];
  return t;
}

// binary-SpMM gather with LDS-cached nz byte-offsets; va via NORMAL cached loads
// (fresh because of the per-round acquire fence; 3x per-XCD L2 reuse captured)
template <int NS>
__device__ __forceinline__ void gather_lds(const int* Sidx, const int* lofs, const int* lcnt,
                                           int mbase,
                                           const int* __restrict__ gptr,
                                           const int* __restrict__ gidx,
                                           const _Float16* __restrict__ va, int rowlim,
                                           int b, int nb, _Float16* Xh, _Float16* Xl, int tid) {
  int seg = tid & 15;
  const char* vab = (const char*)va + seg * 16;
  for (int r = tid >> 4; r < NS * 16; r += 32) {
    float a[8];
#pragma unroll
    for (int e = 0; e < 8; ++e) a[e] = 0.f;
    int lo = lofs[mbase + r], c = lcnt[mbase + r];
    if (lo >= 0) {
      const int* ip = Sidx + lo;
      int p = 0;
      for (; p + 8 <= c; p += 8) {
        half8 v0 = *(const half8*)(vab + ip[p]);
        half8 v1 = *(const half8*)(vab + ip[p + 1]);
        half8 v2 = *(const half8*)(vab + ip[p + 2]);
        half8 v3 = *(const half8*)(vab + ip[p + 3]);
        half8 v4 = *(const half8*)(vab + ip[p + 4]);
        half8 v5 = *(const half8*)(vab + ip[p + 5]);
        half8 v6 = *(const half8*)(vab + ip[p + 6]);
        half8 v7 = *(const half8*)(vab + ip[p + 7]);
#pragma unroll
        for (int e = 0; e < 8; ++e)
          a[e] += (((float)v0[e] + (float)v1[e]) + ((float)v2[e] + (float)v3[e])) +
                  (((float)v4[e] + (float)v5[e]) + ((float)v6[e] + (float)v7[e]));
      }
      for (; p + 2 <= c; p += 2) {
        half8 v0 = *(const half8*)(vab + ip[p]);
        half8 v1 = *(const half8*)(vab + ip[p + 1]);
#pragma unroll
        for (int e = 0; e < 8; ++e) a[e] += (float)v0[e] + (float)v1[e];
      }
      if (p < c) {
        half8 v = *(const half8*)(vab + ip[p]);
#pragma unroll
        for (int e = 0; e < 8; ++e) a[e] += (float)v[e];
      }
    } else {
      int row = b + r * nb;
      if (row < rowlim) {
        int s0 = gptr[row], e_ = gptr[row + 1];
        for (int p = s0; p < e_; ++p) {
          half8 v = *(const half8*)(va + (size_t)gidx[p] * DIM + seg * 8);
#pragma unroll
          for (int e = 0; e < 8; ++e) a[e] += (float)v[e];
        }
      }
    }
    int aoff = sw_idx(r, seg * 8);
#pragma unroll
    for (int e = 0; e < 8; ++e) {
      _Float16 hi = (_Float16)a[e];
      Xh[aoff + e] = hi;
      Xl[aoff + e] = (_Float16)(a[e] - (float)hi);
    }
  }
}

// split-A x f16-B: 2 MFMAs per product
__device__ __forceinline__ void mfma2(f32x4& acc, half8 ah, half8 al, half8 bh) {
  acc = __builtin_amdgcn_mfma_f32_16x16x32_f16(ah, bh, acc, 0, 0, 0);
  acc = __builtin_amdgcn_mfma_f32_16x16x32_f16(al, bh, acc, 0, 0, 0);
}

// one MLP layer: NS 16-row subtiles, 8 waves; wave w owns col tile w (16 cols)
template <int NS>
__device__ __forceinline__ void mlp_layer_t(const _Float16* Ah_, const _Float16* Al_,
                                            const _Float16* __restrict__ Wh,
                                            const float* __restrict__ B,
                                            _Float16* Dh, _Float16* Dl, int tid) {
  int lane = tid & 63, w = tid >> 6;
  int m16 = lane & 15, quad = lane >> 4;
  float bv = B[w * 16 + m16];
  f32x4 acc[NS];
#pragma unroll
  for (int s = 0; s < NS; ++s) acc[s] = (f32x4){bv, bv, bv, bv};
#pragma unroll
  for (int ks = 0; ks < 4; ++ks) {
    int boff = ((w * 4 + ks) * 64 + lane) * 8;
    half8 bh = *(const half8*)(Wh + boff);
#pragma unroll
    for (int s = 0; s < NS; ++s) {
      int a_off = sw_idx(s * 16 + m16, ks * 32 + quad * 8);
      mfma2(acc[s], *(const half8*)(Ah_ + a_off), *(const half8*)(Al_ + a_off), bh);
    }
  }
#pragma unroll
  for (int s = 0; s < NS; ++s)
#pragma unroll
    for (int reg = 0; reg < 4; ++reg) {
      int rl = s * 16 + quad * 4 + reg;
      int col = w * 16 + m16;
      float x = fmaxf(acc[s][reg], 0.f);
      _Float16 hi = (_Float16)x;
      int a = sw_idx(rl, col);
      Dh[a] = hi;
      Dl[a] = (_Float16)(x - (float)hi);
    }
  __syncthreads();
}

// 3-layer MLP: input Ah/Al preserved; T1/T2 scratch; final -> f16 global via bypass stores
template <int NS>
__device__ __forceinline__ void mlp_pers(const _Float16* Ah, const _Float16* Al,
                                         _Float16* T1h, _Float16* T1l,
                                         _Float16* T2h, _Float16* T2l,
                                         const _Float16* __restrict__ W1h, const float* __restrict__ b1,
                                         const _Float16* __restrict__ W2h, const float* __restrict__ b2,
                                         const _Float16* __restrict__ W3h, const float* __restrict__ b3,
                                         _Float16* __restrict__ out, int rowlim, int b, int nb,
                                         int tid) {
  mlp_layer_t<NS>(Ah, Al, W1h, b1, T1h, T1l, tid);
  mlp_layer_t<NS>(T1h, T1l, W2h, b2, T2h, T2l, tid);
  int lane = tid & 63, w = tid >> 6;
  int m16 = lane & 15, quad = lane >> 4;
  float bv = b3[w * 16 + m16];
  f32x4 acc[NS];
#pragma unroll
  for (int s = 0; s < NS; ++s) acc[s] = (f32x4){bv, bv, bv, bv};
#pragma unroll
  for (int ks = 0; ks < 4; ++ks) {
    int boff = ((w * 4 + ks) * 64 + lane) * 8;
    half8 bh = *(const half8*)(W3h + boff);
#pragma unroll
    for (int s = 0; s < NS; ++s) {
      int a_off = sw_idx(s * 16 + m16, ks * 32 + quad * 8);
      mfma2(acc[s], *(const half8*)(T2h + a_off), *(const half8*)(T2l + a_off), bh);
    }
  }
#pragma unroll
  for (int s = 0; s < NS; ++s)
#pragma unroll
    for (int reg = 0; reg < 4; ++reg) {
      int rl = s * 16 + quad * 4 + reg;
      int row = b + rl * nb;
      int col = w * 16 + m16;
      if (row < rowlim) st_bypass(out + (size_t)row * DIM + col, (_Float16)acc[s][reg]);
    }
}

// LSTM gate matmuls with A-fragment hoisting
template <int NS>
__device__ __forceinline__ void lstm_pers(const _Float16* Hh, const _Float16* Hl,
                                          const _Float16* Xh, const _Float16* Xl,
                                          const _Float16* __restrict__ Wxh,
                                          const _Float16* __restrict__ Whh_,
                                          const float* __restrict__ bcomb, int tid,
                                          f32x4 (&acc)[NS][4]) {
  int lane = tid & 63, w = tid >> 6;
  int m16 = lane & 15, quad = lane >> 4;
#pragma unroll
  for (int g = 0; g < 4; ++g) {
    float bv = bcomb[g * 128 + w * 16 + m16];
#pragma unroll
    for (int s = 0; s < NS; ++s) acc[s][g] = (f32x4){bv, bv, bv, bv};
  }
#pragma unroll
  for (int ks = 0; ks < 4; ++ks) {
    half8 ah[NS], al[NS];
#pragma unroll
    for (int s = 0; s < NS; ++s) {
      int a_off = sw_idx(s * 16 + m16, ks * 32 + quad * 8);
      ah[s] = *(const half8*)(Hh + a_off);
      al[s] = *(const half8*)(Hl + a_off);
    }
#pragma unroll
    for (int g = 0; g < 4; ++g) {
      int boff = (((g * 8 + w) * 4 + ks) * 64 + lane) * 8;
      half8 bh = *(const half8*)(Whh_ + boff);
#pragma unroll
      for (int s = 0; s < NS; ++s) mfma2(acc[s][g], ah[s], al[s], bh);
    }
#pragma unroll
    for (int s = 0; s < NS; ++s) {
      int a_off = sw_idx(s * 16 + m16, ks * 32 + quad * 8);
      ah[s] = *(const half8*)(Xh + a_off);
      al[s] = *(const half8*)(Xl + a_off);
    }
#pragma unroll
    for (int g = 0; g < 4; ++g) {
      int boff = (((g * 8 + w) * 4 + ks) * 64 + lane) * 8;
      half8 bh = *(const half8*)(Wxh + boff);
#pragma unroll
      for (int s = 0; s < NS; ++s) mfma2(acc[s][g], ah[s], al[s], bh);
    }
  }
}

// ---------------- fence-free device barrier ----------------
// va stores are write-through atomics, so the barrier itself needs no cache ops:
// drain this wave's stores (vmcnt) before signaling. Slot stores are per-block;
// block 0 polls slots, publishes 'go'. Bounded spins (bug => wrong answer, no hang).
#define GO_IDX (NB * 16)
__device__ __forceinline__ void gbar(unsigned* __restrict__ bar, int nblocks, unsigned ep,
                                     int b, int tid) {
  asm volatile("s_waitcnt vmcnt(0)" ::: "memory");  // our bypass-stores reached L3
  __syncthreads();
  if (b == 0) {
    if (tid < 64) {
      int guard = 0;
      for (;;) {
        int ok = 1;
        for (int s = 1 + tid; s < nblocks; s += 64) {
          unsigned v = __hip_atomic_load(&bar[s * 16], __ATOMIC_RELAXED, __HIP_MEMORY_SCOPE_AGENT);
          ok &= (int)(v >= ep);
        }
        if (__all(ok)) break;
        __builtin_amdgcn_s_sleep(2);
        if (++guard > (1 << 15)) break;  // safety valve
      }
      if (tid == 0)
        __hip_atomic_store(&bar[GO_IDX], ep, __ATOMIC_RELAXED, __HIP_MEMORY_SCOPE_AGENT);
    }
  } else if (tid == 0) {
    __hip_atomic_store(&bar[b * 16], ep, __ATOMIC_RELAXED, __HIP_MEMORY_SCOPE_AGENT);
    int guard = 0;
    while (__hip_atomic_load(&bar[GO_IDX], __ATOMIC_RELAXED, __HIP_MEMORY_SCOPE_AGENT) < ep) {
      __builtin_amdgcn_s_sleep(8);
      if (++guard > (1 << 17)) break;  // safety valve
    }
  }
  __syncthreads();
}

#define SZ128 (DIM * DIM)
#define SZ512 (4 * DIM * DIM)
#define O_CM1 0
#define O_CM2 (SZ128)
#define O_CM3 (2 * SZ128)
#define O_PM1 (3 * SZ128)
#define O_PM2 (4 * SZ128)
#define O_PM3 (5 * SZ128)
#define O_VUX ((size_t)6 * SZ128)
#define O_VUH ((size_t)6 * SZ128 + SZ512)
#define O_NUX ((size_t)6 * SZ128 + 2 * SZ512)
#define O_NUH ((size_t)6 * SZ128 + 3 * SZ512)

// LDS: 6 x 6912 x 2B (split-f16 tiles) + idx pool + meta = ~98KB -> 1 block/CU.
#define LSLOT (3 * 2048 + 768)

// ---------------- persistent kernel: all 120 rounds, h in LDS, c in VGPRs ----------------
template <int NS1>
__global__ __launch_bounds__(512, 2) void persist_kernel(
    const int* __restrict__ row_ptr, const int* __restrict__ col_idx,
    const int* __restrict__ col_ptr, const int* __restrict__ row_idx,
    const int* __restrict__ values, const float* __restrict__ tW, const float* __restrict__ tb,
    const float* __restrict__ fW, const float* __restrict__ fb,
    const _Float16* __restrict__ packh,
    const float* __restrict__ vu_b, const float* __restrict__ nu_b,
    const float* __restrict__ cm_b1, const float* __restrict__ cm_b2,
    const float* __restrict__ cm_b3, const float* __restrict__ pm_b1,
    const float* __restrict__ pm_b2, const float* __restrict__ pm_b3,
    _Float16* __restrict__ va1, _Float16* __restrict__ va2,
    float* __restrict__ hout, unsigned* __restrict__ bar,
    int n_nodes, int N, int nblocks) {
  __shared__ _Float16 Hh[LSLOT], Hl[LSLOT], Xh[LSLOT], Xl[LSLOT], T2h[LSLOT], T2l[LSLOT];
  __shared__ int Sidx[IDXCAP];
  __shared__ int lofs[96], lcnt[96], gstb[96];
  int tid = threadIdx.x, b = blockIdx.x;
  int lane = tid & 63, w = tid >> 6, m16 = lane & 15, quad = lane >> 4;

  const _Float16* CM1 = packh + O_CM1;
  const _Float16* CM2 = packh + O_CM2;
  const _Float16* CM3 = packh + O_CM3;
  const _Float16* PM1 = packh + O_PM1;
  const _Float16* PM2 = packh + O_PM2;
  const _Float16* PM3 = packh + O_PM3;
  const _Float16* VUX = packh + O_VUX;
  const _Float16* VUH = packh + O_VUH;
  const _Float16* NUX = packh + O_NUX;
  const _Float16* NUH = packh + O_NUH;

  // persistent cell state in registers; persistent h (split f16) in LDS
  float cold[3][4];
#pragma unroll
  for (int s = 0; s < 3; ++s)
#pragma unroll
    for (int reg = 0; reg < 4; ++reg) {
      cold[s][reg] = 0.f;
      int rl = s * 16 + quad * 4 + reg;
      int row = b + rl * nblocks;
      int col = w * 16 + m16;
      float hv = 0.f;
      if (row < N) hv = (values[row] == 1) ? (tW[col] + tb[col]) : (fW[col] + fb[col]);
      int a = sw_idx(rl, col);
      _Float16 hi = (_Float16)hv;
      Hh[a] = hi;
      Hl[a] = (_Float16)(hv - (float)hi);
    }

  // ---- stage this block's static nz lists into LDS (once) ----
  // slots [0,48): phase-1 CSR rows; [48,96): phase-2 CSC rows. Stored as byte offsets.
  if (tid < 96) {
    int s = tid, row, c = 0, gs = 0;
    if (s < 48) {
      row = b + s * nblocks;
      if (row < n_nodes) { gs = row_ptr[row]; c = row_ptr[row + 1] - gs; }
    } else {
      row = b + (s - 48) * nblocks;
      if (row < N) { gs = col_ptr[row]; c = col_ptr[row + 1] - gs; }
    }
    gstb[s] = gs;
    lcnt[s] = c;
  }
  __syncthreads();
  if (tid == 0) {
    int cur = 0;
    for (int s = 0; s < 96; ++s) {
      int c = lcnt[s];
      if (c > 0 && cur + c <= IDXCAP) { lofs[s] = cur; cur += c; }
      else if (c > 0) lofs[s] = -1;   // overflow: global fallback for this row
      else lofs[s] = 0;
    }
  }
  __syncthreads();
  for (int s = 0; s < 96; ++s) {
    int c = lcnt[s], lo = lofs[s];
    if (lo < 0 || c == 0) continue;
    int gs = gstb[s];
    const int* src = (s < 48) ? col_idx : row_idx;
    for (int i = tid; i < c; i += 512) Sidx[lo + i] = src[gs + i] << 8;  // *256B
  }
  __syncthreads();

  unsigned ep = 0;
  // phase 0: va1 = cm_mlp(h0) over all rows
  {
    float tpf = touch(CM1, DIM * DIM, tid) + touch(CM2, DIM * DIM, tid) +
                touch(CM3, DIM * DIM, tid);
    asm volatile("" :: "v"(tpf));
  }
  mlp_pers<3>(Hh, Hl, Xh, Xl, T2h, T2l, CM1, cm_b1, CM2, cm_b2, CM3, cm_b3,
              va1, N, b, nblocks, tid);
  gbar(bar, nblocks, ++ep, b, tid);

  for (int r = 0; r < NROUNDS; ++r) {
    // ONE acquire fence per round: invalidate local L1/L2 so all va lines read below
    // are fresh fills from the coherence point (producers write through before their
    // barrier). Weights/idx refetch once per round -- cheap vs per-phase nukes.
    __builtin_amdgcn_fence(__ATOMIC_ACQUIRE, "agent");

    // ---- phase 1: vu-LSTM(CSR gather va1) on node rows + pm-MLP -> va2 ----
    {
      float tpf = touch(VUX, 4 * DIM * DIM, tid) + touch(VUH, 4 * DIM * DIM, tid) +
                  touch(PM1, DIM * DIM, tid) + touch(PM2, DIM * DIM, tid) +
                  touch(PM3, DIM * DIM, tid);
      gather_lds<NS1>(Sidx, lofs, lcnt, 0, row_ptr, col_idx, va1, n_nodes, b, nblocks,
                      Xh, Xl, tid);
      asm volatile("" :: "v"(tpf));
    }
    __syncthreads();
    {
      f32x4 acc[NS1][4];
      lstm_pers<NS1>(Hh, Hl, Xh, Xl, VUX, VUH, vu_b, tid, acc);
      __syncthreads();  // all waves done reading Hh/Xh before h overwrite
#pragma unroll
      for (int s = 0; s < NS1; ++s)
#pragma unroll
        for (int reg = 0; reg < 4; ++reg) {
          int rl = s * 16 + quad * 4 + reg;
          int row = b + rl * nblocks;
          if (row < n_nodes) {
            float iv = sigf(acc[s][0][reg]);
            float fv = sigf(acc[s][1][reg]);
            float gv = tanh_fast(acc[s][2][reg]);
            float ov = sigf(acc[s][3][reg]);
            float cn = fv * cold[s][reg] + iv * gv;
            cold[s][reg] = cn;
            float hn = ov * tanh_fast(cn);
            int a = sw_idx(rl, w * 16 + m16);
            _Float16 hi = (_Float16)hn;
            Hh[a] = hi;
            Hl[a] = (_Float16)(hn - (float)hi);
          }
        }
    }
    __syncthreads();
    mlp_pers<NS1>(Hh, Hl, Xh, Xl, T2h, T2l, PM1, pm_b1, PM2, pm_b2, PM3, pm_b3,
                  va2, n_nodes, b, nblocks, tid);
    gbar(bar, nblocks, ++ep, b, tid);

    // ---- phase 2: nu-LSTM(CSC gather va2) on all rows (+ cm-MLP -> va1 unless last) ----
    // va2 lines were dropped by this round's fence and not read-cached since -> fresh.
    bool last = (r == NROUNDS - 1);
    {
      float tpf = touch(NUX, 4 * DIM * DIM, tid) + touch(NUH, 4 * DIM * DIM, tid) +
                  touch(CM1, DIM * DIM, tid) + touch(CM2, DIM * DIM, tid) +
                  touch(CM3, DIM * DIM, tid);
      gather_lds<3>(Sidx, lofs, lcnt, 48, col_ptr, row_idx, va2, N, b, nblocks, Xh, Xl, tid);
      asm volatile("" :: "v"(tpf));
    }
    __syncthreads();
    {
      f32x4 acc[3][4];
      lstm_pers<3>(Hh, Hl, Xh, Xl, NUX, NUH, nu_b, tid, acc);
      __syncthreads();
#pragma unroll
      for (int s = 0; s < 3; ++s)
#pragma unroll
        for (int reg = 0; reg < 4; ++reg) {
          int rl = s * 16 + quad * 4 + reg;
          int row = b + rl * nblocks;
          if (row < N) {
            float iv = sigf(acc[s][0][reg]);
            float fv = sigf(acc[s][1][reg]);
            float gv = tanh_fast(acc[s][2][reg]);
            float ov = sigf(acc[s][3][reg]);
            float cn = fv * cold[s][reg] + iv * gv;
            cold[s][reg] = cn;
            float hn = ov * tanh_fast(cn);
            if (last) {
              hout[(size_t)row * DIM + (w * 16 + m16)] = hn;
            } else {
              int a = sw_idx(rl, w * 16 + m16);
              _Float16 hi = (_Float16)hn;
              Hh[a] = hi;
              Hl[a] = (_Float16)(hn - (float)hi);
            }
          }
        }
    }
    if (!last) {
      __syncthreads();
      mlp_pers<3>(Hh, Hl, Xh, Xl, T2h, T2l, CM1, cm_b1, CM2, cm_b2, CM3, cm_b3,
                  va1, N, b, nblocks, tid);
      gbar(bar, nblocks, ++ep, b, tid);
    }
  }
}

// ---------------- final vote MLP (fp32, runs once) ----------------
__device__ __forceinline__ void tile_gemm(const float* S, const float* __restrict__ W,
                                          int colB, int rowB, float acc[4][4]) {
#pragma unroll 4
  for (int kc = 0; kc < DIM; kc += 4) {
    float4 xv[4], wv[4];
#pragma unroll
    for (int r = 0; r < 4; ++r) xv[r] = *(const float4*)(S + (rowB + r) * DIM + kc);
#pragma unroll
    for (int c = 0; c < 4; ++c) wv[c] = *(const float4*)(W + (size_t)(colB + c) * DIM + kc);
#pragma unroll
    for (int r = 0; r < 4; ++r)
#pragma unroll
      for (int c = 0; c < 4; ++c)
        acc[r][c] += xv[r].x * wv[c].x + xv[r].y * wv[c].y + xv[r].z * wv[c].z + xv[r].w * wv[c].w;
  }
}

__device__ __forceinline__ void layer_lds(const float* Sin, float* Sout,
                                          const float* __restrict__ W, const float* __restrict__ B,
                                          bool relu, int colB, int rowB) {
  float acc[4][4];
#pragma unroll
  for (int r = 0; r < 4; ++r)
#pragma unroll
    for (int cc = 0; cc < 4; ++cc) acc[r][cc] = B[colB + cc];
  tile_gemm(Sin, W, colB, rowB, acc);
#pragma unroll
  for (int r = 0; r < 4; ++r) {
    float4 v;
    v.x = acc[r][0]; v.y = acc[r][1]; v.z = acc[r][2]; v.w = acc[r][3];
    if (relu) { v.x = fmaxf(v.x, 0.f); v.y = fmaxf(v.y, 0.f); v.z = fmaxf(v.z, 0.f); v.w = fmaxf(v.w, 0.f); }
    *(float4*)&Sout[(rowB + r) * DIM + colB] = v;
  }
  __syncthreads();
}

__global__ __launch_bounds__(256) void vote_kernel(
    const float* __restrict__ X, int M,
    const float* __restrict__ W1, const float* __restrict__ b1,
    const float* __restrict__ W2, const float* __restrict__ b2,
    const float* __restrict__ W3, const float* __restrict__ b3,
    float* __restrict__ out) {
  __shared__ float Xs[32 * DIM];
  __shared__ float Ys[32 * DIM];
  int tid = threadIdx.x;
  int rb = blockIdx.x * 32;
  int mrows = M - rb; if (mrows > 32) mrows = 32;
  {
    const float4* src = (const float4*)(X + (size_t)rb * DIM);
    float4* dst = (float4*)Xs;
    int nf4 = mrows * (DIM / 4);
    for (int t = tid; t < 32 * (DIM / 4); t += 256) {
      float4 v;
      if (t < nf4) v = src[t];
      else { v.x = v.y = v.z = v.w = 0.f; }
      dst[t] = v;
    }
  }
  __syncthreads();
  int tx = tid & 31, ty = tid >> 5;
  int colB = tx * 4, rowB = ty * 4;
  layer_lds(Xs, Ys, W1, b1, true, colB, rowB);
  layer_lds(Ys, Xs, W2, b2, true, colB, rowB);
  if (tid < 32) {
    int gr = rb + tid;
    if (gr < M) {
      float s = b3[0];
      for (int k = 0; k < DIM; ++k) s += Xs[tid * DIM + k] * W3[k];
      out[gr] = s;
    }
  }
}

extern "C" void kernel_launch(void* const* d_in, const int* in_sizes, int n_in,
                              void* d_out, int out_size, void* d_ws, size_t ws_size,
                              hipStream_t stream) {
  const float* adj    = (const float*)d_in[0];
  const int*   values = (const int*)d_in[1];
  const int N       = in_sizes[1];                  // 9000
  const int n_nodes = in_sizes[0] / N;              // 8000
  const int n_vars  = N - n_nodes;                  // 1000

  const float* true_W  = (const float*)d_in[3];
  const float* true_b  = (const float*)d_in[4];
  const float* false_W = (const float*)d_in[5];
  const float* false_b = (const float*)d_in[6];
  const float* cm_W1 = (const float*)d_in[7];
  const float* cm_b1 = (const float*)d_in[8];
  const float* cm_W2 = (const float*)d_in[9];
  const float* cm_b2 = (const float*)d_in[10];
  const float* cm_W3 = (const float*)d_in[11];
  const float* cm_b3 = (const float*)d_in[12];
  const float* pm_W1 = (const float*)d_in[13];
  const float* pm_b1 = (const float*)d_in[14];
  const float* pm_W2 = (const float*)d_in[15];
  const float* pm_b2 = (const float*)d_in[16];
  const float* pm_W3 = (const float*)d_in[17];
  const float* pm_b3 = (const float*)d_in[18];
  const float* vv_W1 = (const float*)d_in[19];
  const float* vv_b1 = (const float*)d_in[20];
  const float* vv_W2 = (const float*)d_in[21];
  const float* vv_b2 = (const float*)d_in[22];
  const float* vv_W3 = (const float*)d_in[23];
  const float* vv_b3 = (const float*)d_in[24];
  const float* vu_Wih = (const float*)d_in[25];
  const float* vu_Whh = (const float*)d_in[26];
  const float* vu_bih = (const float*)d_in[27];
  const float* vu_bhh = (const float*)d_in[28];
  const float* nu_Wih = (const float*)d_in[29];
  const float* nu_Whh = (const float*)d_in[30];
  const float* nu_bih = (const float*)d_in[31];
  const float* nu_bhh = (const float*)d_in[32];

  uintptr_t p = (uintptr_t)d_ws;
  auto take = [&](size_t bytes) -> void* {
    uintptr_t cur = (p + 255) & ~(uintptr_t)255;
    p = cur + bytes;
    return (void*)cur;
  };
  float* h   = (float*)take((size_t)N * DIM * sizeof(float));
  _Float16* va1 = (_Float16*)take((size_t)N * DIM * sizeof(_Float16));
  _Float16* va2 = (_Float16*)take((size_t)N * DIM * sizeof(_Float16));
  int* row_ptr = (int*)take((size_t)(n_nodes + 1) * sizeof(int));
  int* col_ptr = (int*)take((size_t)(N + 1) * sizeof(int));
  int* cnts    = (int*)take((size_t)(n_nodes + N) * sizeof(int));
  int* row_cnt = cnts;
  int* col_cnt = cnts + n_nodes;
  int* col_cur = (int*)take((size_t)N * sizeof(int));
  int* col_idx = (int*)take((size_t)NNZ_CAP * sizeof(int));
  int* row_idx = (int*)take((size_t)NNZ_CAP * sizeof(int));

  size_t tot_pack = (size_t)6 * SZ128 + (size_t)4 * SZ512;
  _Float16* packh = (_Float16*)take(tot_pack * sizeof(_Float16));
  float* vu_b = (float*)take(512 * sizeof(float));
  float* nu_b = (float*)take(512 * sizeof(float));
  unsigned* bar = (unsigned*)take((size_t)(NB + 2) * 16 * sizeof(unsigned));

  hipMemsetAsync(cnts, 0, (size_t)(n_nodes + N) * sizeof(int), stream);
  hipMemsetAsync(bar, 0, (size_t)(NB + 2) * 16 * sizeof(unsigned), stream);

  int cols4 = (N + 3) / 4;
  dim3 cgrid(n_nodes, (cols4 + 255) / 256);
  count_nz_kernel<<<cgrid, 256, 0, stream>>>(adj, row_cnt, col_cnt, N);
  scan_kernel<<<1, 256, 0, stream>>>(row_cnt, row_ptr, n_nodes);
  scan_kernel<<<1, 256, 0, stream>>>(col_cnt, col_ptr, N);
  copy_int_kernel<<<(N + 255) / 256, 256, 0, stream>>>(col_ptr, col_cur, N);
  fill_csr_csc_kernel<<<n_nodes, 64, 0, stream>>>(adj, row_ptr, col_idx, col_cur, row_idx, N);

  auto pack = [&](const float* src, int out_dim, size_t o) {
    pack_w_kernel<<<(out_dim * DIM + 255) / 256, 256, 0, stream>>>(src, out_dim, packh + o);
  };
  pack(cm_W1, DIM, O_CM1); pack(cm_W2, DIM, O_CM2); pack(cm_W3, DIM, O_CM3);
  pack(pm_W1, DIM, O_PM1); pack(pm_W2, DIM, O_PM2); pack(pm_W3, DIM, O_PM3);
  pack(vu_Wih, 4 * DIM, O_VUX); pack(vu_Whh, 4 * DIM, O_VUH);
  pack(nu_Wih, 4 * DIM, O_NUX); pack(nu_Whh, 4 * DIM, O_NUH);
  pack_bias_kernel<<<2, 256, 0, stream>>>(vu_bih, vu_bhh, vu_b, 512);
  pack_bias_kernel<<<2, 256, 0, stream>>>(nu_bih, nu_bhh, nu_b, 512);

  // persistent kernel: NB blocks, forced 1/CU by LDS footprint -> all co-resident
  int ns1 = (n_nodes + NB * 16 - 1) / (NB * 16);  // node-row subtiles (2 for 8000/250)
  if (ns1 <= 2) {
    persist_kernel<2><<<NB, 512, 0, stream>>>(
        row_ptr, col_idx, col_ptr, row_idx, values, true_W, true_b, false_W, false_b,
        packh, vu_b, nu_b, cm_b1, cm_b2, cm_b3, pm_b1, pm_b2, pm_b3,
        va1, va2, h, bar, n_nodes, N, NB);
  } else {
    persist_kernel<3><<<NB, 512, 0, stream>>>(
        row_ptr, col_idx, col_ptr, row_idx, values, true_W, true_b, false_W, false_b,
        packh, vu_b, nu_b, cm_b1, cm_b2, cm_b3, pm_b1, pm_b2, pm_b3,
        va1, va2, h, bar, n_nodes, N, NB);
  }

  vote_kernel<<<(n_vars + 31) / 32, 256, 0, stream>>>(h + (size_t)n_nodes * DIM, n_vars,
      vv_W1, vv_b1, vv_W2, vv_b2, vv_W3, vv_b3, (float*)d_out);
}

// Round 6
// 10846.972 us; speedup vs baseline: 1.1714x; 1.1714x over previous
//
#include <hip/hip_runtime.h>
#include <cstddef>
#include <cstdint>

#define DIM 128
#define NROUNDS 120
#define NNZ_CAP (1 << 20)
#define NB 250  // persistent grid: 250 blocks, forced 1/CU via LDS footprint (<=256 CUs)
#define IDXCAP 3584  // LDS nz-index pool (ints); per-block avg ~2050, tail ~2600

typedef _Float16 half8 __attribute__((ext_vector_type(8)));
typedef float f32x4 __attribute__((ext_vector_type(4)));
typedef unsigned long long u64;

__device__ __forceinline__ float sigf(float x) { return 1.f / (1.f + __expf(-x)); }
__device__ __forceinline__ float tanh_fast(float x) { return 2.f / (1.f + __expf(-2.f * x)) - 1.f; }

// ---- cross-XCD va access ----
// READ: one 16B uncached load (sc0 sc1 -> bypass L1/L2, served by coherent L3).
// Halves fabric transaction count vs 2x8B atomic loads (same bytes). Consumers MUST
// execute s_waitcnt vmcnt(0) + sched_barrier(0) before reading the result (rule #18).
__device__ __forceinline__ void ld16(half8& d, const void* a) {
  asm volatile("global_load_dwordx4 %0, %1, off sc0 sc1" : "=&v"(d) : "v"(a));
}
__device__ __forceinline__ void ld_wait() {
  asm volatile("s_waitcnt vmcnt(0)" ::: "memory");
  __builtin_amdgcn_sched_barrier(0);
}
// WRITE: agent-scope relaxed atomic 2B store (write-through to L3, no local allocate).
__device__ __forceinline__ void st_bypass(_Float16* p, _Float16 v) {
  union { _Float16 f; unsigned short s; } u;
  u.f = v;
  __hip_atomic_store((unsigned short*)p, u.s, __ATOMIC_RELAXED, __HIP_MEMORY_SCOPE_AGENT);
}

// ---------------- sparse build ----------------
__global__ void count_nz_kernel(const float* __restrict__ adj, int* __restrict__ row_cnt,
                                int* __restrict__ col_cnt, int ncols) {
  int i = blockIdx.x;
  int t4 = blockIdx.y * blockDim.x + threadIdx.x;
  int j0 = t4 * 4;
  int c = 0;
  if (j0 < ncols) {
    if ((ncols & 3) == 0) {
      float4 v = *(const float4*)(adj + (size_t)i * ncols + j0);
      if (v.x != 0.f) { atomicAdd(&col_cnt[j0 + 0], 1); ++c; }
      if (v.y != 0.f) { atomicAdd(&col_cnt[j0 + 1], 1); ++c; }
      if (v.z != 0.f) { atomicAdd(&col_cnt[j0 + 2], 1); ++c; }
      if (v.w != 0.f) { atomicAdd(&col_cnt[j0 + 3], 1); ++c; }
    } else {
      for (int e = 0; e < 4 && j0 + e < ncols; ++e)
        if (adj[(size_t)i * ncols + j0 + e] != 0.f) { atomicAdd(&col_cnt[j0 + e], 1); ++c; }
    }
  }
  for (int off = 32; off; off >>= 1) c += __shfl_down(c, off, 64);
  if ((threadIdx.x & 63) == 0 && c) atomicAdd(&row_cnt[i], c);
}

__global__ void scan_kernel(const int* __restrict__ cnt, int* __restrict__ ptr, int n) {
  __shared__ int sdata[256];
  int t = threadIdx.x;
  int per = (n + 255) / 256;
  int beg = t * per;
  int end = beg + per; if (end > n) end = n;
  int local = 0;
  for (int i = beg; i < end; ++i) local += cnt[i];
  sdata[t] = local;
  __syncthreads();
  for (int off = 1; off < 256; off <<= 1) {
    int v = (t >= off) ? sdata[t - off] : 0;
    __syncthreads();
    sdata[t] += v;
    __syncthreads();
  }
  int run = sdata[t] - local;
  for (int i = beg; i < end; ++i) { ptr[i] = run; run += cnt[i]; }
  if (t == 255) ptr[n] = sdata[255];
}

__global__ void copy_int_kernel(const int* __restrict__ a, int* __restrict__ b, int n) {
  int i = blockIdx.x * 256 + threadIdx.x;
  if (i < n) b[i] = a[i];
}

// CSR fill (deterministic order) + CSC fill via atomic column cursors
__global__ __launch_bounds__(64) void fill_csr_csc_kernel(const float* __restrict__ adj,
                                                          const int* __restrict__ row_ptr,
                                                          int* __restrict__ col_idx,
                                                          int* __restrict__ col_cur,
                                                          int* __restrict__ row_idx, int ncols) {
  int row = blockIdx.x;
  int lane = threadIdx.x;
  int base = row_ptr[row];
  int cursor = 0;
  const float* arow = adj + (size_t)row * ncols;
  for (int j0 = 0; j0 < ncols; j0 += 64) {
    int j = j0 + lane;
    bool nz = (j < ncols) && (arow[j] != 0.f);
    u64 m = __ballot(nz);
    int pre = __popcll(m & ((1ull << lane) - 1));
    if (nz) {
      col_idx[base + cursor + pre] = j;
      int t = atomicAdd(&col_cur[j], 1);
      row_idx[t] = row;
    }
    cursor += __popcll(m);
  }
}

// ---------------- weight packing: MFMA 16x16x32 B-fragment order (f16 only) ----------------
__global__ void pack_w_kernel(const float* __restrict__ src, int out_dim,
                              _Float16* __restrict__ dh) {
  int idx = blockIdx.x * 256 + threadIdx.x;
  if (idx >= out_dim * DIM) return;
  int n = idx >> 7, k = idx & 127;
  _Float16 hi = (_Float16)src[idx];
  int nt = n >> 4, ks = k >> 5;
  int L = ((k >> 3) & 3) * 16 + (n & 15);
  int j = k & 7;
  dh[((nt * 4 + ks) * 64 + L) * 8 + j] = hi;
}

__global__ void pack_bias_kernel(const float* __restrict__ a, const float* __restrict__ b,
                                 float* __restrict__ o, int n) {
  int i = blockIdx.x * 256 + threadIdx.x;
  if (i < n) o[i] = a[i] + b[i];
}

// ---------------- LDS swizzle (rows x 128, 8-chunk XOR) ----------------
__device__ __forceinline__ int sw_idx(int m, int k) {
  return (m << 7) + (((((k >> 3) ^ (m & 15))) << 3) | (k & 7));
}

// L2-warm touch: independent line loads covering w[0..n) at 128B stride
__device__ __forceinline__ float touch(const _Float16* __restrict__ w, int n, int tid) {
  float t = 0.f;
  for (int i = tid * 64; i < n; i += 512 * 64) t += (float)w[i];
  return t;
}

// binary-SpMM gather with LDS-cached nz byte-offsets; va via 16B uncached loads
template <int NS>
__device__ __forceinline__ void gather_lds(const int* Sidx, const int* lofs, const int* lcnt,
                                           int mbase,
                                           const int* __restrict__ gptr,
                                           const int* __restrict__ gidx,
                                           const _Float16* __restrict__ va, int rowlim,
                                           int b, int nb, _Float16* Xh, _Float16* Xl, int tid) {
  int seg = tid & 15;
  const char* vab = (const char*)va + seg * 16;
  for (int r = tid >> 4; r < NS * 16; r += 32) {
    float a[8];
#pragma unroll
    for (int e = 0; e < 8; ++e) a[e] = 0.f;
    int lo = lofs[mbase + r], c = lcnt[mbase + r];
    if (lo >= 0) {
      const int* ip = Sidx + lo;
      int p = 0;
      for (; p + 8 <= c; p += 8) {
        half8 v0, v1, v2, v3, v4, v5, v6, v7;
        ld16(v0, vab + ip[p]);
        ld16(v1, vab + ip[p + 1]);
        ld16(v2, vab + ip[p + 2]);
        ld16(v3, vab + ip[p + 3]);
        ld16(v4, vab + ip[p + 4]);
        ld16(v5, vab + ip[p + 5]);
        ld16(v6, vab + ip[p + 6]);
        ld16(v7, vab + ip[p + 7]);
        ld_wait();
#pragma unroll
        for (int e = 0; e < 8; ++e)
          a[e] += (((float)v0[e] + (float)v1[e]) + ((float)v2[e] + (float)v3[e])) +
                  (((float)v4[e] + (float)v5[e]) + ((float)v6[e] + (float)v7[e]));
      }
      for (; p + 2 <= c; p += 2) {
        half8 v0, v1;
        ld16(v0, vab + ip[p]);
        ld16(v1, vab + ip[p + 1]);
        ld_wait();
#pragma unroll
        for (int e = 0; e < 8; ++e) a[e] += (float)v0[e] + (float)v1[e];
      }
      if (p < c) {
        half8 v;
        ld16(v, vab + ip[p]);
        ld_wait();
#pragma unroll
        for (int e = 0; e < 8; ++e) a[e] += (float)v[e];
      }
    } else {
      int row = b + r * nb;
      if (row < rowlim) {
        int s0 = gptr[row], e_ = gptr[row + 1];
        for (int p = s0; p < e_; ++p) {
          half8 v;
          ld16(v, va + (size_t)gidx[p] * DIM + seg * 8);
          ld_wait();
#pragma unroll
          for (int e = 0; e < 8; ++e) a[e] += (float)v[e];
        }
      }
    }
    int aoff = sw_idx(r, seg * 8);
#pragma unroll
    for (int e = 0; e < 8; ++e) {
      _Float16 hi = (_Float16)a[e];
      Xh[aoff + e] = hi;
      Xl[aoff + e] = (_Float16)(a[e] - (float)hi);
    }
  }
}

// split-A x f16-B: 2 MFMAs per product
__device__ __forceinline__ void mfma2(f32x4& acc, half8 ah, half8 al, half8 bh) {
  acc = __builtin_amdgcn_mfma_f32_16x16x32_f16(ah, bh, acc, 0, 0, 0);
  acc = __builtin_amdgcn_mfma_f32_16x16x32_f16(al, bh, acc, 0, 0, 0);
}

// one MLP layer: NS 16-row subtiles, 8 waves; wave w owns col tile w (16 cols)
template <int NS>
__device__ __forceinline__ void mlp_layer_t(const _Float16* Ah_, const _Float16* Al_,
                                            const _Float16* __restrict__ Wh,
                                            const float* __restrict__ B,
                                            _Float16* Dh, _Float16* Dl, int tid) {
  int lane = tid & 63, w = tid >> 6;
  int m16 = lane & 15, quad = lane >> 4;
  float bv = B[w * 16 + m16];
  f32x4 acc[NS];
#pragma unroll
  for (int s = 0; s < NS; ++s) acc[s] = (f32x4){bv, bv, bv, bv};
#pragma unroll
  for (int ks = 0; ks < 4; ++ks) {
    int boff = ((w * 4 + ks) * 64 + lane) * 8;
    half8 bh = *(const half8*)(Wh + boff);
#pragma unroll
    for (int s = 0; s < NS; ++s) {
      int a_off = sw_idx(s * 16 + m16, ks * 32 + quad * 8);
      mfma2(acc[s], *(const half8*)(Ah_ + a_off), *(const half8*)(Al_ + a_off), bh);
    }
  }
#pragma unroll
  for (int s = 0; s < NS; ++s)
#pragma unroll
    for (int reg = 0; reg < 4; ++reg) {
      int rl = s * 16 + quad * 4 + reg;
      int col = w * 16 + m16;
      float x = fmaxf(acc[s][reg], 0.f);
      _Float16 hi = (_Float16)x;
      int a = sw_idx(rl, col);
      Dh[a] = hi;
      Dl[a] = (_Float16)(x - (float)hi);
    }
  __syncthreads();
}

// 3-layer MLP: input Ah/Al preserved; T1/T2 scratch; final -> f16 global via bypass stores
template <int NS>
__device__ __forceinline__ void mlp_pers(const _Float16* Ah, const _Float16* Al,
                                         _Float16* T1h, _Float16* T1l,
                                         _Float16* T2h, _Float16* T2l,
                                         const _Float16* __restrict__ W1h, const float* __restrict__ b1,
                                         const _Float16* __restrict__ W2h, const float* __restrict__ b2,
                                         const _Float16* __restrict__ W3h, const float* __restrict__ b3,
                                         _Float16* __restrict__ out, int rowlim, int b, int nb,
                                         int tid) {
  mlp_layer_t<NS>(Ah, Al, W1h, b1, T1h, T1l, tid);
  mlp_layer_t<NS>(T1h, T1l, W2h, b2, T2h, T2l, tid);
  int lane = tid & 63, w = tid >> 6;
  int m16 = lane & 15, quad = lane >> 4;
  float bv = b3[w * 16 + m16];
  f32x4 acc[NS];
#pragma unroll
  for (int s = 0; s < NS; ++s) acc[s] = (f32x4){bv, bv, bv, bv};
#pragma unroll
  for (int ks = 0; ks < 4; ++ks) {
    int boff = ((w * 4 + ks) * 64 + lane) * 8;
    half8 bh = *(const half8*)(W3h + boff);
#pragma unroll
    for (int s = 0; s < NS; ++s) {
      int a_off = sw_idx(s * 16 + m16, ks * 32 + quad * 8);
      mfma2(acc[s], *(const half8*)(T2h + a_off), *(const half8*)(T2l + a_off), bh);
    }
  }
#pragma unroll
  for (int s = 0; s < NS; ++s)
#pragma unroll
    for (int reg = 0; reg < 4; ++reg) {
      int rl = s * 16 + quad * 4 + reg;
      int row = b + rl * nb;
      int col = w * 16 + m16;
      if (row < rowlim) st_bypass(out + (size_t)row * DIM + col, (_Float16)acc[s][reg]);
    }
}

// LSTM gate matmuls with A-fragment hoisting
template <int NS>
__device__ __forceinline__ void lstm_pers(const _Float16* Hh, const _Float16* Hl,
                                          const _Float16* Xh, const _Float16* Xl,
                                          const _Float16* __restrict__ Wxh,
                                          const _Float16* __restrict__ Whh_,
                                          const float* __restrict__ bcomb, int tid,
                                          f32x4 (&acc)[NS][4]) {
  int lane = tid & 63, w = tid >> 6;
  int m16 = lane & 15, quad = lane >> 4;
#pragma unroll
  for (int g = 0; g < 4; ++g) {
    float bv = bcomb[g * 128 + w * 16 + m16];
#pragma unroll
    for (int s = 0; s < NS; ++s) acc[s][g] = (f32x4){bv, bv, bv, bv};
  }
#pragma unroll
  for (int ks = 0; ks < 4; ++ks) {
    half8 ah[NS], al[NS];
#pragma unroll
    for (int s = 0; s < NS; ++s) {
      int a_off = sw_idx(s * 16 + m16, ks * 32 + quad * 8);
      ah[s] = *(const half8*)(Hh + a_off);
      al[s] = *(const half8*)(Hl + a_off);
    }
#pragma unroll
    for (int g = 0; g < 4; ++g) {
      int boff = (((g * 8 + w) * 4 + ks) * 64 + lane) * 8;
      half8 bh = *(const half8*)(Whh_ + boff);
#pragma unroll
      for (int s = 0; s < NS; ++s) mfma2(acc[s][g], ah[s], al[s], bh);
    }
#pragma unroll
    for (int s = 0; s < NS; ++s) {
      int a_off = sw_idx(s * 16 + m16, ks * 32 + quad * 8);
      ah[s] = *(const half8*)(Xh + a_off);
      al[s] = *(const half8*)(Xl + a_off);
    }
#pragma unroll
    for (int g = 0; g < 4; ++g) {
      int boff = (((g * 8 + w) * 4 + ks) * 64 + lane) * 8;
      half8 bh = *(const half8*)(Wxh + boff);
#pragma unroll
      for (int s = 0; s < NS; ++s) mfma2(acc[s][g], ah[s], al[s], bh);
    }
  }
}

// ---------------- fence-free device barrier ----------------
// va stores are write-through atomics: drain via vmcnt before signaling; no cache ops.
// Per-block arrival slots; block 0 polls, publishes 'go'. Bounded spins (no hangs).
#define GO_IDX (NB * 16)
__device__ __forceinline__ void gbar(unsigned* __restrict__ bar, int nblocks, unsigned ep,
                                     int b, int tid) {
  asm volatile("s_waitcnt vmcnt(0)" ::: "memory");  // our bypass-stores reached L3
  __syncthreads();
  if (b == 0) {
    if (tid < 64) {
      int guard = 0;
      for (;;) {
        int ok = 1;
        for (int s = 1 + tid; s < nblocks; s += 64) {
          unsigned v = __hip_atomic_load(&bar[s * 16], __ATOMIC_RELAXED, __HIP_MEMORY_SCOPE_AGENT);
          ok &= (int)(v >= ep);
        }
        if (__all(ok)) break;
        __builtin_amdgcn_s_sleep(2);
        if (++guard > (1 << 15)) break;  // safety valve
      }
      if (tid == 0)
        __hip_atomic_store(&bar[GO_IDX], ep, __ATOMIC_RELAXED, __HIP_MEMORY_SCOPE_AGENT);
    }
  } else if (tid == 0) {
    __hip_atomic_store(&bar[b * 16], ep, __ATOMIC_RELAXED, __HIP_MEMORY_SCOPE_AGENT);
    int guard = 0;
    while (__hip_atomic_load(&bar[GO_IDX], __ATOMIC_RELAXED, __HIP_MEMORY_SCOPE_AGENT) < ep) {
      __builtin_amdgcn_s_sleep(8);
      if (++guard > (1 << 17)) break;  // safety valve
    }
  }
  __syncthreads();
}

#define SZ128 (DIM * DIM)
#define SZ512 (4 * DIM * DIM)
#define O_CM1 0
#define O_CM2 (SZ128)
#define O_CM3 (2 * SZ128)
#define O_PM1 (3 * SZ128)
#define O_PM2 (4 * SZ128)
#define O_PM3 (5 * SZ128)
#define O_VUX ((size_t)6 * SZ128)
#define O_VUH ((size_t)6 * SZ128 + SZ512)
#define O_NUX ((size_t)6 * SZ128 + 2 * SZ512)
#define O_NUH ((size_t)6 * SZ128 + 3 * SZ512)

// LDS: 6 x 6912 x 2B (split-f16 tiles) + idx pool + meta = ~98KB -> 1 block/CU.
#define LSLOT (3 * 2048 + 768)

// ---------------- persistent kernel: all 120 rounds, h in LDS, c in VGPRs ----------------
template <int NS1>
__global__ __launch_bounds__(512, 2) void persist_kernel(
    const int* __restrict__ row_ptr, const int* __restrict__ col_idx,
    const int* __restrict__ col_ptr, const int* __restrict__ row_idx,
    const int* __restrict__ values, const float* __restrict__ tW, const float* __restrict__ tb,
    const float* __restrict__ fW, const float* __restrict__ fb,
    const _Float16* __restrict__ packh,
    const float* __restrict__ vu_b, const float* __restrict__ nu_b,
    const float* __restrict__ cm_b1, const float* __restrict__ cm_b2,
    const float* __restrict__ cm_b3, const float* __restrict__ pm_b1,
    const float* __restrict__ pm_b2, const float* __restrict__ pm_b3,
    _Float16* __restrict__ va1, _Float16* __restrict__ va2,
    float* __restrict__ hout, unsigned* __restrict__ bar,
    int n_nodes, int N, int nblocks) {
  __shared__ _Float16 Hh[LSLOT], Hl[LSLOT], Xh[LSLOT], Xl[LSLOT], T2h[LSLOT], T2l[LSLOT];
  __shared__ int Sidx[IDXCAP];
  __shared__ int lofs[96], lcnt[96], gstb[96];
  int tid = threadIdx.x, b = blockIdx.x;
  int lane = tid & 63, w = tid >> 6, m16 = lane & 15, quad = lane >> 4;

  const _Float16* CM1 = packh + O_CM1;
  const _Float16* CM2 = packh + O_CM2;
  const _Float16* CM3 = packh + O_CM3;
  const _Float16* PM1 = packh + O_PM1;
  const _Float16* PM2 = packh + O_PM2;
  const _Float16* PM3 = packh + O_PM3;
  const _Float16* VUX = packh + O_VUX;
  const _Float16* VUH = packh + O_VUH;
  const _Float16* NUX = packh + O_NUX;
  const _Float16* NUH = packh + O_NUH;

  // persistent cell state in registers; persistent h (split f16) in LDS
  float cold[3][4];
#pragma unroll
  for (int s = 0; s < 3; ++s)
#pragma unroll
    for (int reg = 0; reg < 4; ++reg) {
      cold[s][reg] = 0.f;
      int rl = s * 16 + quad * 4 + reg;
      int row = b + rl * nblocks;
      int col = w * 16 + m16;
      float hv = 0.f;
      if (row < N) hv = (values[row] == 1) ? (tW[col] + tb[col]) : (fW[col] + fb[col]);
      int a = sw_idx(rl, col);
      _Float16 hi = (_Float16)hv;
      Hh[a] = hi;
      Hl[a] = (_Float16)(hv - (float)hi);
    }

  // ---- stage this block's static nz lists into LDS (once) ----
  // slots [0,48): phase-1 CSR rows; [48,96): phase-2 CSC rows. Stored as byte offsets.
  if (tid < 96) {
    int s = tid, row, c = 0, gs = 0;
    if (s < 48) {
      row = b + s * nblocks;
      if (row < n_nodes) { gs = row_ptr[row]; c = row_ptr[row + 1] - gs; }
    } else {
      row = b + (s - 48) * nblocks;
      if (row < N) { gs = col_ptr[row]; c = col_ptr[row + 1] - gs; }
    }
    gstb[s] = gs;
    lcnt[s] = c;
  }
  __syncthreads();
  if (tid == 0) {
    int cur = 0;
    for (int s = 0; s < 96; ++s) {
      int c = lcnt[s];
      if (c > 0 && cur + c <= IDXCAP) { lofs[s] = cur; cur += c; }
      else if (c > 0) lofs[s] = -1;   // overflow: global fallback for this row
      else lofs[s] = 0;
    }
  }
  __syncthreads();
  for (int s = 0; s < 96; ++s) {
    int c = lcnt[s], lo = lofs[s];
    if (lo < 0 || c == 0) continue;
    int gs = gstb[s];
    const int* src = (s < 48) ? col_idx : row_idx;
    for (int i = tid; i < c; i += 512) Sidx[lo + i] = src[gs + i] << 8;  // *256B
  }
  __syncthreads();

  unsigned ep = 0;
  // phase 0: va1 = cm_mlp(h0) over all rows
  {
    float tpf = touch(CM1, DIM * DIM, tid) + touch(CM2, DIM * DIM, tid) +
                touch(CM3, DIM * DIM, tid);
    asm volatile("" :: "v"(tpf));
  }
  mlp_pers<3>(Hh, Hl, Xh, Xl, T2h, T2l, CM1, cm_b1, CM2, cm_b2, CM3, cm_b3,
              va1, N, b, nblocks, tid);
  gbar(bar, nblocks, ++ep, b, tid);

  for (int r = 0; r < NROUNDS; ++r) {
    // ---- phase 1: vu-LSTM(CSR gather va1) on node rows + pm-MLP -> va2 ----
    {
      gather_lds<NS1>(Sidx, lofs, lcnt, 0, row_ptr, col_idx, va1, n_nodes, b, nblocks,
                      Xh, Xl, tid);
      float tpf = touch(VUX, 4 * DIM * DIM, tid) + touch(VUH, 4 * DIM * DIM, tid) +
                  touch(PM1, DIM * DIM, tid) + touch(PM2, DIM * DIM, tid) +
                  touch(PM3, DIM * DIM, tid);
      asm volatile("" :: "v"(tpf));
    }
    __syncthreads();
    {
      f32x4 acc[NS1][4];
      lstm_pers<NS1>(Hh, Hl, Xh, Xl, VUX, VUH, vu_b, tid, acc);
      __syncthreads();  // all waves done reading Hh/Xh before h overwrite
#pragma unroll
      for (int s = 0; s < NS1; ++s)
#pragma unroll
        for (int reg = 0; reg < 4; ++reg) {
          int rl = s * 16 + quad * 4 + reg;
          int row = b + rl * nblocks;
          if (row < n_nodes) {
            float iv = sigf(acc[s][0][reg]);
            float fv = sigf(acc[s][1][reg]);
            float gv = tanh_fast(acc[s][2][reg]);
            float ov = sigf(acc[s][3][reg]);
            float cn = fv * cold[s][reg] + iv * gv;
            cold[s][reg] = cn;
            float hn = ov * tanh_fast(cn);
            int a = sw_idx(rl, w * 16 + m16);
            _Float16 hi = (_Float16)hn;
            Hh[a] = hi;
            Hl[a] = (_Float16)(hn - (float)hi);
          }
        }
    }
    __syncthreads();
    mlp_pers<NS1>(Hh, Hl, Xh, Xl, T2h, T2l, PM1, pm_b1, PM2, pm_b2, PM3, pm_b3,
                  va2, n_nodes, b, nblocks, tid);
    gbar(bar, nblocks, ++ep, b, tid);

    // ---- phase 2: nu-LSTM(CSC gather va2) on all rows (+ cm-MLP -> va1 unless last) ----
    bool last = (r == NROUNDS - 1);
    {
      gather_lds<3>(Sidx, lofs, lcnt, 48, col_ptr, row_idx, va2, N, b, nblocks, Xh, Xl, tid);
      float tpf = touch(NUX, 4 * DIM * DIM, tid) + touch(NUH, 4 * DIM * DIM, tid) +
                  touch(CM1, DIM * DIM, tid) + touch(CM2, DIM * DIM, tid) +
                  touch(CM3, DIM * DIM, tid);
      asm volatile("" :: "v"(tpf));
    }
    __syncthreads();
    {
      f32x4 acc[3][4];
      lstm_pers<3>(Hh, Hl, Xh, Xl, NUX, NUH, nu_b, tid, acc);
      __syncthreads();
#pragma unroll
      for (int s = 0; s < 3; ++s)
#pragma unroll
        for (int reg = 0; reg < 4; ++reg) {
          int rl = s * 16 + quad * 4 + reg;
          int row = b + rl * nblocks;
          if (row < N) {
            float iv = sigf(acc[s][0][reg]);
            float fv = sigf(acc[s][1][reg]);
            float gv = tanh_fast(acc[s][2][reg]);
            float ov = sigf(acc[s][3][reg]);
            float cn = fv * cold[s][reg] + iv * gv;
            cold[s][reg] = cn;
            float hn = ov * tanh_fast(cn);
            if (last) {
              hout[(size_t)row * DIM + (w * 16 + m16)] = hn;
            } else {
              int a = sw_idx(rl, w * 16 + m16);
              _Float16 hi = (_Float16)hn;
              Hh[a] = hi;
              Hl[a] = (_Float16)(hn - (float)hi);
            }
          }
        }
    }
    if (!last) {
      __syncthreads();
      mlp_pers<3>(Hh, Hl, Xh, Xl, T2h, T2l, CM1, cm_b1, CM2, cm_b2, CM3, cm_b3,
                  va1, N, b, nblocks, tid);
      gbar(bar, nblocks, ++ep, b, tid);
    }
  }
}

// ---------------- final vote MLP (fp32, runs once) ----------------
__device__ __forceinline__ void tile_gemm(const float* S, const float* __restrict__ W,
                                          int colB, int rowB, float acc[4][4]) {
#pragma unroll 4
  for (int kc = 0; kc < DIM; kc += 4) {
    float4 xv[4], wv[4];
#pragma unroll
    for (int r = 0; r < 4; ++r) xv[r] = *(const float4*)(S + (rowB + r) * DIM + kc);
#pragma unroll
    for (int c = 0; c < 4; ++c) wv[c] = *(const float4*)(W + (size_t)(colB + c) * DIM + kc);
#pragma unroll
    for (int r = 0; r < 4; ++r)
#pragma unroll
      for (int c = 0; c < 4; ++c)
        acc[r][c] += xv[r].x * wv[c].x + xv[r].y * wv[c].y + xv[r].z * wv[c].z + xv[r].w * wv[c].w;
  }
}

__device__ __forceinline__ void layer_lds(const float* Sin, float* Sout,
                                          const float* __restrict__ W, const float* __restrict__ B,
                                          bool relu, int colB, int rowB) {
  float acc[4][4];
#pragma unroll
  for (int r = 0; r < 4; ++r)
#pragma unroll
    for (int cc = 0; cc < 4; ++cc) acc[r][cc] = B[colB + cc];
  tile_gemm(Sin, W, colB, rowB, acc);
#pragma unroll
  for (int r = 0; r < 4; ++r) {
    float4 v;
    v.x = acc[r][0]; v.y = acc[r][1]; v.z = acc[r][2]; v.w = acc[r][3];
    if (relu) { v.x = fmaxf(v.x, 0.f); v.y = fmaxf(v.y, 0.f); v.z = fmaxf(v.z, 0.f); v.w = fmaxf(v.w, 0.f); }
    *(float4*)&Sout[(rowB + r) * DIM + colB] = v;
  }
  __syncthreads();
}

__global__ __launch_bounds__(256) void vote_kernel(
    const float* __restrict__ X, int M,
    const float* __restrict__ W1, const float* __restrict__ b1,
    const float* __restrict__ W2, const float* __restrict__ b2,
    const float* __restrict__ W3, const float* __restrict__ b3,
    float* __restrict__ out) {
  __shared__ float Xs[32 * DIM];
  __shared__ float Ys[32 * DIM];
  int tid = threadIdx.x;
  int rb = blockIdx.x * 32;
  int mrows = M - rb; if (mrows > 32) mrows = 32;
  {
    const float4* src = (const float4*)(X + (size_t)rb * DIM);
    float4* dst = (float4*)Xs;
    int nf4 = mrows * (DIM / 4);
    for (int t = tid; t < 32 * (DIM / 4); t += 256) {
      float4 v;
      if (t < nf4) v = src[t];
      else { v.x = v.y = v.z = v.w = 0.f; }
      dst[t] = v;
    }
  }
  __syncthreads();
  int tx = tid & 31, ty = tid >> 5;
  int colB = tx * 4, rowB = ty * 4;
  layer_lds(Xs, Ys, W1, b1, true, colB, rowB);
  layer_lds(Ys, Xs, W2, b2, true, colB, rowB);
  if (tid < 32) {
    int gr = rb + tid;
    if (gr < M) {
      float s = b3[0];
      for (int k = 0; k < DIM; ++k) s += Xs[tid * DIM + k] * W3[k];
      out[gr] = s;
    }
  }
}

extern "C" void kernel_launch(void* const* d_in, const int* in_sizes, int n_in,
                              void* d_out, int out_size, void* d_ws, size_t ws_size,
                              hipStream_t stream) {
  const float* adj    = (const float*)d_in[0];
  const int*   values = (const int*)d_in[1];
  const int N       = in_sizes[1];                  // 9000
  const int n_nodes = in_sizes[0] / N;              // 8000
  const int n_vars  = N - n_nodes;                  // 1000

  const float* true_W  = (const float*)d_in[3];
  const float* true_b  = (const float*)d_in[4];
  const float* false_W = (const float*)d_in[5];
  const float* false_b = (const float*)d_in[6];
  const float* cm_W1 = (const float*)d_in[7];
  const float* cm_b1 = (const float*)d_in[8];
  const float* cm_W2 = (const float*)d_in[9];
  const float* cm_b2 = (const float*)d_in[10];
  const float* cm_W3 = (const float*)d_in[11];
  const float* cm_b3 = (const float*)d_in[12];
  const float* pm_W1 = (const float*)d_in[13];
  const float* pm_b1 = (const float*)d_in[14];
  const float* pm_W2 = (const float*)d_in[15];
  const float* pm_b2 = (const float*)d_in[16];
  const float* pm_W3 = (const float*)d_in[17];
  const float* pm_b3 = (const float*)d_in[18];
  const float* vv_W1 = (const float*)d_in[19];
  const float* vv_b1 = (const float*)d_in[20];
  const float* vv_W2 = (const float*)d_in[21];
  const float* vv_b2 = (const float*)d_in[22];
  const float* vv_W3 = (const float*)d_in[23];
  const float* vv_b3 = (const float*)d_in[24];
  const float* vu_Wih = (const float*)d_in[25];
  const float* vu_Whh = (const float*)d_in[26];
  const float* vu_bih = (const float*)d_in[27];
  const float* vu_bhh = (const float*)d_in[28];
  const float* nu_Wih = (const float*)d_in[29];
  const float* nu_Whh = (const float*)d_in[30];
  const float* nu_bih = (const float*)d_in[31];
  const float* nu_bhh = (const float*)d_in[32];

  uintptr_t p = (uintptr_t)d_ws;
  auto take = [&](size_t bytes) -> void* {
    uintptr_t cur = (p + 255) & ~(uintptr_t)255;
    p = cur + bytes;
    return (void*)cur;
  };
  float* h   = (float*)take((size_t)N * DIM * sizeof(float));
  _Float16* va1 = (_Float16*)take((size_t)N * DIM * sizeof(_Float16));
  _Float16* va2 = (_Float16*)take((size_t)N * DIM * sizeof(_Float16));
  int* row_ptr = (int*)take((size_t)(n_nodes + 1) * sizeof(int));
  int* col_ptr = (int*)take((size_t)(N + 1) * sizeof(int));
  int* cnts    = (int*)take((size_t)(n_nodes + N) * sizeof(int));
  int* row_cnt = cnts;
  int* col_cnt = cnts + n_nodes;
  int* col_cur = (int*)take((size_t)N * sizeof(int));
  int* col_idx = (int*)take((size_t)NNZ_CAP * sizeof(int));
  int* row_idx = (int*)take((size_t)NNZ_CAP * sizeof(int));

  size_t tot_pack = (size_t)6 * SZ128 + (size_t)4 * SZ512;
  _Float16* packh = (_Float16*)take(tot_pack * sizeof(_Float16));
  float* vu_b = (float*)take(512 * sizeof(float));
  float* nu_b = (float*)take(512 * sizeof(float));
  unsigned* bar = (unsigned*)take((size_t)(NB + 2) * 16 * sizeof(unsigned));

  hipMemsetAsync(cnts, 0, (size_t)(n_nodes + N) * sizeof(int), stream);
  hipMemsetAsync(bar, 0, (size_t)(NB + 2) * 16 * sizeof(unsigned), stream);

  int cols4 = (N + 3) / 4;
  dim3 cgrid(n_nodes, (cols4 + 255) / 256);
  count_nz_kernel<<<cgrid, 256, 0, stream>>>(adj, row_cnt, col_cnt, N);
  scan_kernel<<<1, 256, 0, stream>>>(row_cnt, row_ptr, n_nodes);
  scan_kernel<<<1, 256, 0, stream>>>(col_cnt, col_ptr, N);
  copy_int_kernel<<<(N + 255) / 256, 256, 0, stream>>>(col_ptr, col_cur, N);
  fill_csr_csc_kernel<<<n_nodes, 64, 0, stream>>>(adj, row_ptr, col_idx, col_cur, row_idx, N);

  auto pack = [&](const float* src, int out_dim, size_t o) {
    pack_w_kernel<<<(out_dim * DIM + 255) / 256, 256, 0, stream>>>(src, out_dim, packh + o);
  };
  pack(cm_W1, DIM, O_CM1); pack(cm_W2, DIM, O_CM2); pack(cm_W3, DIM, O_CM3);
  pack(pm_W1, DIM, O_PM1); pack(pm_W2, DIM, O_PM2); pack(pm_W3, DIM, O_PM3);
  pack(vu_Wih, 4 * DIM, O_VUX); pack(vu_Whh, 4 * DIM, O_VUH);
  pack(nu_Wih, 4 * DIM, O_NUX); pack(nu_Whh, 4 * DIM, O_NUH);
  pack_bias_kernel<<<2, 256, 0, stream>>>(vu_bih, vu_bhh, vu_b, 512);
  pack_bias_kernel<<<2, 256, 0, stream>>>(nu_bih, nu_bhh, nu_b, 512);

  // persistent kernel: NB blocks, forced 1/CU by LDS footprint -> all co-resident
  int ns1 = (n_nodes + NB * 16 - 1) / (NB * 16);  // node-row subtiles (2 for 8000/250)
  if (ns1 <= 2) {
    persist_kernel<2><<<NB, 512, 0, stream>>>(
        row_ptr, col_idx, col_ptr, row_idx, values, true_W, true_b, false_W, false_b,
        packh, vu_b, nu_b, cm_b1, cm_b2, cm_b3, pm_b1, pm_b2, pm_b3,
        va1, va2, h, bar, n_nodes, N, NB);
  } else {
    persist_kernel<3><<<NB, 512, 0, stream>>>(
        row_ptr, col_idx, col_ptr, row_idx, values, true_W, true_b, false_W, false_b,
        packh, vu_b, nu_b, cm_b1, cm_b2, cm_b3, pm_b1, pm_b2, pm_b3,
        va1, va2, h, bar, n_nodes, N, NB);
  }

  vote_kernel<<<(n_vars + 31) / 32, 256, 0, stream>>>(h + (size_t)n_nodes * DIM, n_vars,
      vv_W1, vv_b1, vv_W2, vv_b2, vv_W3, vv_b3, (float*)d_out);
}

// Round 7
// 10311.665 us; speedup vs baseline: 1.2322x; 1.0519x over previous
//
#include <hip/hip_runtime.h>
#include <cstddef>
#include <cstdint>

#define DIM 128
#define NROUNDS 120
#define NNZ_CAP (1 << 20)
#define NB 250  // persistent grid: 250 blocks, forced 1/CU via LDS footprint (<=256 CUs)
#define IDXCAP 3584  // LDS nz-index pool (ints); per-block avg ~2050, tail ~2600
#define RING 6  // va address-rotation depth: slot reused after 12 phases >> L2 lifetime

typedef _Float16 half8 __attribute__((ext_vector_type(8)));
typedef float f32x4 __attribute__((ext_vector_type(4)));
typedef unsigned long long u64;

__device__ __forceinline__ float sigf(float x) { return 1.f / (1.f + __expf(-x)); }
__device__ __forceinline__ float tanh_fast(float x) { return 2.f / (1.f + __expf(-2.f * x)) - 1.f; }

// ---- va WRITES: agent-scope relaxed atomic 2B stores (write-through to coherence
// point, no local allocate). va READS: plain CACHED loads (L1/L2/L3 allocate) --
// correct WITHOUT fences because each round uses a fresh ring slot (address
// rotation): a slot's address is re-read only after 12 phases of L2 churn. ----
__device__ __forceinline__ void st_bypass(_Float16* p, _Float16 v) {
  union { _Float16 f; unsigned short s; } u;
  u.f = v;
  __hip_atomic_store((unsigned short*)p, u.s, __ATOMIC_RELAXED, __HIP_MEMORY_SCOPE_AGENT);
}

// ---------------- sparse build ----------------
__global__ void count_nz_kernel(const float* __restrict__ adj, int* __restrict__ row_cnt,
                                int* __restrict__ col_cnt, int ncols) {
  int i = blockIdx.x;
  int t4 = blockIdx.y * blockDim.x + threadIdx.x;
  int j0 = t4 * 4;
  int c = 0;
  if (j0 < ncols) {
    if ((ncols & 3) == 0) {
      float4 v = *(const float4*)(adj + (size_t)i * ncols + j0);
      if (v.x != 0.f) { atomicAdd(&col_cnt[j0 + 0], 1); ++c; }
      if (v.y != 0.f) { atomicAdd(&col_cnt[j0 + 1], 1); ++c; }
      if (v.z != 0.f) { atomicAdd(&col_cnt[j0 + 2], 1); ++c; }
      if (v.w != 0.f) { atomicAdd(&col_cnt[j0 + 3], 1); ++c; }
    } else {
      for (int e = 0; e < 4 && j0 + e < ncols; ++e)
        if (adj[(size_t)i * ncols + j0 + e] != 0.f) { atomicAdd(&col_cnt[j0 + e], 1); ++c; }
    }
  }
  for (int off = 32; off; off >>= 1) c += __shfl_down(c, off, 64);
  if ((threadIdx.x & 63) == 0 && c) atomicAdd(&row_cnt[i], c);
}

__global__ void scan_kernel(const int* __restrict__ cnt, int* __restrict__ ptr, int n) {
  __shared__ int sdata[256];
  int t = threadIdx.x;
  int per = (n + 255) / 256;
  int beg = t * per;
  int end = beg + per; if (end > n) end = n;
  int local = 0;
  for (int i = beg; i < end; ++i) local += cnt[i];
  sdata[t] = local;
  __syncthreads();
  for (int off = 1; off < 256; off <<= 1) {
    int v = (t >= off) ? sdata[t - off] : 0;
    __syncthreads();
    sdata[t] += v;
    __syncthreads();
  }
  int run = sdata[t] - local;
  for (int i = beg; i < end; ++i) { ptr[i] = run; run += cnt[i]; }
  if (t == 255) ptr[n] = sdata[255];
}

__global__ void copy_int_kernel(const int* __restrict__ a, int* __restrict__ b, int n) {
  int i = blockIdx.x * 256 + threadIdx.x;
  if (i < n) b[i] = a[i];
}

// CSR fill (deterministic order) + CSC fill via atomic column cursors
__global__ __launch_bounds__(64) void fill_csr_csc_kernel(const float* __restrict__ adj,
                                                          const int* __restrict__ row_ptr,
                                                          int* __restrict__ col_idx,
                                                          int* __restrict__ col_cur,
                                                          int* __restrict__ row_idx, int ncols) {
  int row = blockIdx.x;
  int lane = threadIdx.x;
  int base = row_ptr[row];
  int cursor = 0;
  const float* arow = adj + (size_t)row * ncols;
  for (int j0 = 0; j0 < ncols; j0 += 64) {
    int j = j0 + lane;
    bool nz = (j < ncols) && (arow[j] != 0.f);
    u64 m = __ballot(nz);
    int pre = __popcll(m & ((1ull << lane) - 1));
    if (nz) {
      col_idx[base + cursor + pre] = j;
      int t = atomicAdd(&col_cur[j], 1);
      row_idx[t] = row;
    }
    cursor += __popcll(m);
  }
}

// ---------------- weight packing: MFMA 16x16x32 B-fragment order (f16 only) ----------------
__global__ void pack_w_kernel(const float* __restrict__ src, int out_dim,
                              _Float16* __restrict__ dh) {
  int idx = blockIdx.x * 256 + threadIdx.x;
  if (idx >= out_dim * DIM) return;
  int n = idx >> 7, k = idx & 127;
  _Float16 hi = (_Float16)src[idx];
  int nt = n >> 4, ks = k >> 5;
  int L = ((k >> 3) & 3) * 16 + (n & 15);
  int j = k & 7;
  dh[((nt * 4 + ks) * 64 + L) * 8 + j] = hi;
}

__global__ void pack_bias_kernel(const float* __restrict__ a, const float* __restrict__ b,
                                 float* __restrict__ o, int n) {
  int i = blockIdx.x * 256 + threadIdx.x;
  if (i < n) o[i] = a[i] + b[i];
}

// ---------------- LDS swizzle (rows x 128, 8-chunk XOR) ----------------
__device__ __forceinline__ int sw_idx(int m, int k) {
  return (m << 7) + (((((k >> 3) ^ (m & 15))) << 3) | (k & 7));
}

// L2-warm touch: independent line loads covering w[0..n) at 128B stride
__device__ __forceinline__ float touch(const _Float16* __restrict__ w, int n, int tid) {
  float t = 0.f;
  for (int i = tid * 64; i < n; i += 512 * 64) t += (float)w[i];
  return t;
}

// binary-SpMM gather with LDS-cached nz byte-offsets; va via CACHED half8 loads
template <int NS>
__device__ __forceinline__ void gather_lds(const int* Sidx, const int* lofs, const int* lcnt,
                                           int mbase,
                                           const int* __restrict__ gptr,
                                           const int* __restrict__ gidx,
                                           const _Float16* __restrict__ va, int rowlim,
                                           int b, int nb, _Float16* Xh, _Float16* Xl, int tid) {
  int seg = tid & 15;
  const char* vab = (const char*)va + seg * 16;
  for (int r = tid >> 4; r < NS * 16; r += 32) {
    float a[8];
#pragma unroll
    for (int e = 0; e < 8; ++e) a[e] = 0.f;
    int lo = lofs[mbase + r], c = lcnt[mbase + r];
    if (lo >= 0) {
      const int* ip = Sidx + lo;
      int p = 0;
      for (; p + 8 <= c; p += 8) {
        half8 v0 = *(const half8*)(vab + ip[p]);
        half8 v1 = *(const half8*)(vab + ip[p + 1]);
        half8 v2 = *(const half8*)(vab + ip[p + 2]);
        half8 v3 = *(const half8*)(vab + ip[p + 3]);
        half8 v4 = *(const half8*)(vab + ip[p + 4]);
        half8 v5 = *(const half8*)(vab + ip[p + 5]);
        half8 v6 = *(const half8*)(vab + ip[p + 6]);
        half8 v7 = *(const half8*)(vab + ip[p + 7]);
#pragma unroll
        for (int e = 0; e < 8; ++e)
          a[e] += (((float)v0[e] + (float)v1[e]) + ((float)v2[e] + (float)v3[e])) +
                  (((float)v4[e] + (float)v5[e]) + ((float)v6[e] + (float)v7[e]));
      }
      for (; p + 2 <= c; p += 2) {
        half8 v0 = *(const half8*)(vab + ip[p]);
        half8 v1 = *(const half8*)(vab + ip[p + 1]);
#pragma unroll
        for (int e = 0; e < 8; ++e) a[e] += (float)v0[e] + (float)v1[e];
      }
      if (p < c) {
        half8 v = *(const half8*)(vab + ip[p]);
#pragma unroll
        for (int e = 0; e < 8; ++e) a[e] += (float)v[e];
      }
    } else {
      int row = b + r * nb;
      if (row < rowlim) {
        int s0 = gptr[row], e_ = gptr[row + 1];
        for (int p = s0; p < e_; ++p) {
          half8 v = *(const half8*)(va + (size_t)gidx[p] * DIM + seg * 8);
#pragma unroll
          for (int e = 0; e < 8; ++e) a[e] += (float)v[e];
        }
      }
    }
    int aoff = sw_idx(r, seg * 8);
#pragma unroll
    for (int e = 0; e < 8; ++e) {
      _Float16 hi = (_Float16)a[e];
      Xh[aoff + e] = hi;
      Xl[aoff + e] = (_Float16)(a[e] - (float)hi);
    }
  }
}

// split-A x f16-B: 2 MFMAs per product
__device__ __forceinline__ void mfma2(f32x4& acc, half8 ah, half8 al, half8 bh) {
  acc = __builtin_amdgcn_mfma_f32_16x16x32_f16(ah, bh, acc, 0, 0, 0);
  acc = __builtin_amdgcn_mfma_f32_16x16x32_f16(al, bh, acc, 0, 0, 0);
}

// one MLP layer: NS 16-row subtiles, 8 waves; wave w owns col tile w (16 cols)
template <int NS>
__device__ __forceinline__ void mlp_layer_t(const _Float16* Ah_, const _Float16* Al_,
                                            const _Float16* __restrict__ Wh,
                                            const float* __restrict__ B,
                                            _Float16* Dh, _Float16* Dl, int tid) {
  int lane = tid & 63, w = tid >> 6;
  int m16 = lane & 15, quad = lane >> 4;
  float bv = B[w * 16 + m16];
  f32x4 acc[NS];
#pragma unroll
  for (int s = 0; s < NS; ++s) acc[s] = (f32x4){bv, bv, bv, bv};
#pragma unroll
  for (int ks = 0; ks < 4; ++ks) {
    int boff = ((w * 4 + ks) * 64 + lane) * 8;
    half8 bh = *(const half8*)(Wh + boff);
#pragma unroll
    for (int s = 0; s < NS; ++s) {
      int a_off = sw_idx(s * 16 + m16, ks * 32 + quad * 8);
      mfma2(acc[s], *(const half8*)(Ah_ + a_off), *(const half8*)(Al_ + a_off), bh);
    }
  }
#pragma unroll
  for (int s = 0; s < NS; ++s)
#pragma unroll
    for (int reg = 0; reg < 4; ++reg) {
      int rl = s * 16 + quad * 4 + reg;
      int col = w * 16 + m16;
      float x = fmaxf(acc[s][reg], 0.f);
      _Float16 hi = (_Float16)x;
      int a = sw_idx(rl, col);
      Dh[a] = hi;
      Dl[a] = (_Float16)(x - (float)hi);
    }
  __syncthreads();
}

// 3-layer MLP: input Ah/Al preserved; T1/T2 scratch; final -> f16 global via bypass stores
template <int NS>
__device__ __forceinline__ void mlp_pers(const _Float16* Ah, const _Float16* Al,
                                         _Float16* T1h, _Float16* T1l,
                                         _Float16* T2h, _Float16* T2l,
                                         const _Float16* __restrict__ W1h, const float* __restrict__ b1,
                                         const _Float16* __restrict__ W2h, const float* __restrict__ b2,
                                         const _Float16* __restrict__ W3h, const float* __restrict__ b3,
                                         _Float16* __restrict__ out, int rowlim, int b, int nb,
                                         int tid) {
  mlp_layer_t<NS>(Ah, Al, W1h, b1, T1h, T1l, tid);
  mlp_layer_t<NS>(T1h, T1l, W2h, b2, T2h, T2l, tid);
  int lane = tid & 63, w = tid >> 6;
  int m16 = lane & 15, quad = lane >> 4;
  float bv = b3[w * 16 + m16];
  f32x4 acc[NS];
#pragma unroll
  for (int s = 0; s < NS; ++s) acc[s] = (f32x4){bv, bv, bv, bv};
#pragma unroll
  for (int ks = 0; ks < 4; ++ks) {
    int boff = ((w * 4 + ks) * 64 + lane) * 8;
    half8 bh = *(const half8*)(W3h + boff);
#pragma unroll
    for (int s = 0; s < NS; ++s) {
      int a_off = sw_idx(s * 16 + m16, ks * 32 + quad * 8);
      mfma2(acc[s], *(const half8*)(T2h + a_off), *(const half8*)(T2l + a_off), bh);
    }
  }
#pragma unroll
  for (int s = 0; s < NS; ++s)
#pragma unroll
    for (int reg = 0; reg < 4; ++reg) {
      int rl = s * 16 + quad * 4 + reg;
      int row = b + rl * nb;
      int col = w * 16 + m16;
      if (row < rowlim) st_bypass(out + (size_t)row * DIM + col, (_Float16)acc[s][reg]);
    }
}

// LSTM gate matmuls with A-fragment hoisting
template <int NS>
__device__ __forceinline__ void lstm_pers(const _Float16* Hh, const _Float16* Hl,
                                          const _Float16* Xh, const _Float16* Xl,
                                          const _Float16* __restrict__ Wxh,
                                          const _Float16* __restrict__ Whh_,
                                          const float* __restrict__ bcomb, int tid,
                                          f32x4 (&acc)[NS][4]) {
  int lane = tid & 63, w = tid >> 6;
  int m16 = lane & 15, quad = lane >> 4;
#pragma unroll
  for (int g = 0; g < 4; ++g) {
    float bv = bcomb[g * 128 + w * 16 + m16];
#pragma unroll
    for (int s = 0; s < NS; ++s) acc[s][g] = (f32x4){bv, bv, bv, bv};
  }
#pragma unroll
  for (int ks = 0; ks < 4; ++ks) {
    half8 ah[NS], al[NS];
#pragma unroll
    for (int s = 0; s < NS; ++s) {
      int a_off = sw_idx(s * 16 + m16, ks * 32 + quad * 8);
      ah[s] = *(const half8*)(Hh + a_off);
      al[s] = *(const half8*)(Hl + a_off);
    }
#pragma unroll
    for (int g = 0; g < 4; ++g) {
      int boff = (((g * 8 + w) * 4 + ks) * 64 + lane) * 8;
      half8 bh = *(const half8*)(Whh_ + boff);
#pragma unroll
      for (int s = 0; s < NS; ++s) mfma2(acc[s][g], ah[s], al[s], bh);
    }
#pragma unroll
    for (int s = 0; s < NS; ++s) {
      int a_off = sw_idx(s * 16 + m16, ks * 32 + quad * 8);
      ah[s] = *(const half8*)(Xh + a_off);
      al[s] = *(const half8*)(Xl + a_off);
    }
#pragma unroll
    for (int g = 0; g < 4; ++g) {
      int boff = (((g * 8 + w) * 4 + ks) * 64 + lane) * 8;
      half8 bh = *(const half8*)(Wxh + boff);
#pragma unroll
      for (int s = 0; s < NS; ++s) mfma2(acc[s][g], ah[s], al[s], bh);
    }
  }
}

// ---------------- fence-free device barrier ----------------
// va stores are write-through atomics: drain via vmcnt before signaling; no cache ops.
// Per-block arrival slots; block 0 polls, publishes 'go'. Bounded spins (no hangs).
#define GO_IDX (NB * 16)
__device__ __forceinline__ void gbar(unsigned* __restrict__ bar, int nblocks, unsigned ep,
                                     int b, int tid) {
  asm volatile("s_waitcnt vmcnt(0)" ::: "memory");  // our bypass-stores reached L3
  __syncthreads();
  if (b == 0) {
    if (tid < 64) {
      int guard = 0;
      for (;;) {
        int ok = 1;
        for (int s = 1 + tid; s < nblocks; s += 64) {
          unsigned v = __hip_atomic_load(&bar[s * 16], __ATOMIC_RELAXED, __HIP_MEMORY_SCOPE_AGENT);
          ok &= (int)(v >= ep);
        }
        if (__all(ok)) break;
        __builtin_amdgcn_s_sleep(2);
        if (++guard > (1 << 15)) break;  // safety valve
      }
      if (tid == 0)
        __hip_atomic_store(&bar[GO_IDX], ep, __ATOMIC_RELAXED, __HIP_MEMORY_SCOPE_AGENT);
    }
  } else if (tid == 0) {
    __hip_atomic_store(&bar[b * 16], ep, __ATOMIC_RELAXED, __HIP_MEMORY_SCOPE_AGENT);
    int guard = 0;
    while (__hip_atomic_load(&bar[GO_IDX], __ATOMIC_RELAXED, __HIP_MEMORY_SCOPE_AGENT) < ep) {
      __builtin_amdgcn_s_sleep(8);
      if (++guard > (1 << 17)) break;  // safety valve
    }
  }
  __syncthreads();
}

#define SZ128 (DIM * DIM)
#define SZ512 (4 * DIM * DIM)
#define O_CM1 0
#define O_CM2 (SZ128)
#define O_CM3 (2 * SZ128)
#define O_PM1 (3 * SZ128)
#define O_PM2 (4 * SZ128)
#define O_PM3 (5 * SZ128)
#define O_VUX ((size_t)6 * SZ128)
#define O_VUH ((size_t)6 * SZ128 + SZ512)
#define O_NUX ((size_t)6 * SZ128 + 2 * SZ512)
#define O_NUH ((size_t)6 * SZ128 + 3 * SZ512)

// LDS: 6 x 6912 x 2B (split-f16 tiles) + idx pool + meta = ~98KB -> 1 block/CU.
#define LSLOT (3 * 2048 + 768)

// ---------------- persistent kernel: all 120 rounds, h in LDS, c in VGPRs ----------------
template <int NS1>
__global__ __launch_bounds__(512, 2) void persist_kernel(
    const int* __restrict__ row_ptr, const int* __restrict__ col_idx,
    const int* __restrict__ col_ptr, const int* __restrict__ row_idx,
    const int* __restrict__ values, const float* __restrict__ tW, const float* __restrict__ tb,
    const float* __restrict__ fW, const float* __restrict__ fb,
    const _Float16* __restrict__ packh,
    const float* __restrict__ vu_b, const float* __restrict__ nu_b,
    const float* __restrict__ cm_b1, const float* __restrict__ cm_b2,
    const float* __restrict__ cm_b3, const float* __restrict__ pm_b1,
    const float* __restrict__ pm_b2, const float* __restrict__ pm_b3,
    _Float16* __restrict__ va1, _Float16* __restrict__ va2, size_t vstride,
    float* __restrict__ hout, unsigned* __restrict__ bar,
    int n_nodes, int N, int nblocks) {
  __shared__ _Float16 Hh[LSLOT], Hl[LSLOT], Xh[LSLOT], Xl[LSLOT], T2h[LSLOT], T2l[LSLOT];
  __shared__ int Sidx[IDXCAP];
  __shared__ int lofs[96], lcnt[96], gstb[96];
  int tid = threadIdx.x, b = blockIdx.x;
  int lane = tid & 63, w = tid >> 6, m16 = lane & 15, quad = lane >> 4;

  const _Float16* CM1 = packh + O_CM1;
  const _Float16* CM2 = packh + O_CM2;
  const _Float16* CM3 = packh + O_CM3;
  const _Float16* PM1 = packh + O_PM1;
  const _Float16* PM2 = packh + O_PM2;
  const _Float16* PM3 = packh + O_PM3;
  const _Float16* VUX = packh + O_VUX;
  const _Float16* VUH = packh + O_VUH;
  const _Float16* NUX = packh + O_NUX;
  const _Float16* NUH = packh + O_NUH;

  // persistent cell state in registers; persistent h (split f16) in LDS
  float cold[3][4];
#pragma unroll
  for (int s = 0; s < 3; ++s)
#pragma unroll
    for (int reg = 0; reg < 4; ++reg) {
      cold[s][reg] = 0.f;
      int rl = s * 16 + quad * 4 + reg;
      int row = b + rl * nblocks;
      int col = w * 16 + m16;
      float hv = 0.f;
      if (row < N) hv = (values[row] == 1) ? (tW[col] + tb[col]) : (fW[col] + fb[col]);
      int a = sw_idx(rl, col);
      _Float16 hi = (_Float16)hv;
      Hh[a] = hi;
      Hl[a] = (_Float16)(hv - (float)hi);
    }

  // ---- stage this block's static nz lists into LDS (once) ----
  // slots [0,48): phase-1 CSR rows; [48,96): phase-2 CSC rows. Stored as byte offsets.
  if (tid < 96) {
    int s = tid, row, c = 0, gs = 0;
    if (s < 48) {
      row = b + s * nblocks;
      if (row < n_nodes) { gs = row_ptr[row]; c = row_ptr[row + 1] - gs; }
    } else {
      row = b + (s - 48) * nblocks;
      if (row < N) { gs = col_ptr[row]; c = col_ptr[row + 1] - gs; }
    }
    gstb[s] = gs;
    lcnt[s] = c;
  }
  __syncthreads();
  if (tid == 0) {
    int cur = 0;
    for (int s = 0; s < 96; ++s) {
      int c = lcnt[s];
      if (c > 0 && cur + c <= IDXCAP) { lofs[s] = cur; cur += c; }
      else if (c > 0) lofs[s] = -1;   // overflow: global fallback for this row
      else lofs[s] = 0;
    }
  }
  __syncthreads();
  for (int s = 0; s < 96; ++s) {
    int c = lcnt[s], lo = lofs[s];
    if (lo < 0 || c == 0) continue;
    int gs = gstb[s];
    const int* src = (s < 48) ? col_idx : row_idx;
    for (int i = tid; i < c; i += 512) Sidx[lo + i] = src[gs + i] << 8;  // *256B
  }
  __syncthreads();

  unsigned ep = 0;
  // phase 0: va1[slot 0] = cm_mlp(h0) over all rows
  {
    float tpf = touch(CM1, DIM * DIM, tid) + touch(CM2, DIM * DIM, tid) +
                touch(CM3, DIM * DIM, tid);
    asm volatile("" :: "v"(tpf));
  }
  mlp_pers<3>(Hh, Hl, Xh, Xl, T2h, T2l, CM1, cm_b1, CM2, cm_b2, CM3, cm_b3,
              va1, N, b, nblocks, tid);
  gbar(bar, nblocks, ++ep, b, tid);

  for (int r = 0; r < NROUNDS; ++r) {
    // ring slots: this round reads va1[r%R], writes va2[r%R]; phase 2 writes va1[(r+1)%R]
    const _Float16* va1r = va1 + (size_t)(r % RING) * vstride;
    _Float16* va2w = va2 + (size_t)(r % RING) * vstride;
    _Float16* va1w = va1 + (size_t)((r + 1) % RING) * vstride;

    // ---- phase 1: vu-LSTM(CSR gather va1) on node rows + pm-MLP -> va2 ----
    {
      gather_lds<NS1>(Sidx, lofs, lcnt, 0, row_ptr, col_idx, va1r, n_nodes, b, nblocks,
                      Xh, Xl, tid);
      float tpf = touch(VUX, 4 * DIM * DIM, tid) + touch(VUH, 4 * DIM * DIM, tid) +
                  touch(PM1, DIM * DIM, tid) + touch(PM2, DIM * DIM, tid) +
                  touch(PM3, DIM * DIM, tid);
      asm volatile("" :: "v"(tpf));
    }
    __syncthreads();
    {
      f32x4 acc[NS1][4];
      lstm_pers<NS1>(Hh, Hl, Xh, Xl, VUX, VUH, vu_b, tid, acc);
      __syncthreads();  // all waves done reading Hh/Xh before h overwrite
#pragma unroll
      for (int s = 0; s < NS1; ++s)
#pragma unroll
        for (int reg = 0; reg < 4; ++reg) {
          int rl = s * 16 + quad * 4 + reg;
          int row = b + rl * nblocks;
          if (row < n_nodes) {
            float iv = sigf(acc[s][0][reg]);
            float fv = sigf(acc[s][1][reg]);
            float gv = tanh_fast(acc[s][2][reg]);
            float ov = sigf(acc[s][3][reg]);
            float cn = fv * cold[s][reg] + iv * gv;
            cold[s][reg] = cn;
            float hn = ov * tanh_fast(cn);
            int a = sw_idx(rl, w * 16 + m16);
            _Float16 hi = (_Float16)hn;
            Hh[a] = hi;
            Hl[a] = (_Float16)(hn - (float)hi);
          }
        }
    }
    __syncthreads();
    mlp_pers<NS1>(Hh, Hl, Xh, Xl, T2h, T2l, PM1, pm_b1, PM2, pm_b2, PM3, pm_b3,
                  va2w, n_nodes, b, nblocks, tid);
    gbar(bar, nblocks, ++ep, b, tid);

    // ---- phase 2: nu-LSTM(CSC gather va2) on all rows (+ cm-MLP -> va1 unless last) ----
    bool last = (r == NROUNDS - 1);
    {
      gather_lds<3>(Sidx, lofs, lcnt, 48, col_ptr, row_idx, va2w, N, b, nblocks, Xh, Xl, tid);
      float tpf = touch(NUX, 4 * DIM * DIM, tid) + touch(NUH, 4 * DIM * DIM, tid) +
                  touch(CM1, DIM * DIM, tid) + touch(CM2, DIM * DIM, tid) +
                  touch(CM3, DIM * DIM, tid);
      asm volatile("" :: "v"(tpf));
    }
    __syncthreads();
    {
      f32x4 acc[3][4];
      lstm_pers<3>(Hh, Hl, Xh, Xl, NUX, NUH, nu_b, tid, acc);
      __syncthreads();
#pragma unroll
      for (int s = 0; s < 3; ++s)
#pragma unroll
        for (int reg = 0; reg < 4; ++reg) {
          int rl = s * 16 + quad * 4 + reg;
          int row = b + rl * nblocks;
          if (row < N) {
            float iv = sigf(acc[s][0][reg]);
            float fv = sigf(acc[s][1][reg]);
            float gv = tanh_fast(acc[s][2][reg]);
            float ov = sigf(acc[s][3][reg]);
            float cn = fv * cold[s][reg] + iv * gv;
            cold[s][reg] = cn;
            float hn = ov * tanh_fast(cn);
            if (last) {
              hout[(size_t)row * DIM + (w * 16 + m16)] = hn;
            } else {
              int a = sw_idx(rl, w * 16 + m16);
              _Float16 hi = (_Float16)hn;
              Hh[a] = hi;
              Hl[a] = (_Float16)(hn - (float)hi);
            }
          }
        }
    }
    if (!last) {
      __syncthreads();
      mlp_pers<3>(Hh, Hl, Xh, Xl, T2h, T2l, CM1, cm_b1, CM2, cm_b2, CM3, cm_b3,
                  va1w, N, b, nblocks, tid);
      gbar(bar, nblocks, ++ep, b, tid);
    }
  }
}

// ---------------- final vote MLP (fp32, runs once) ----------------
__device__ __forceinline__ void tile_gemm(const float* S, const float* __restrict__ W,
                                          int colB, int rowB, float acc[4][4]) {
#pragma unroll 4
  for (int kc = 0; kc < DIM; kc += 4) {
    float4 xv[4], wv[4];
#pragma unroll
    for (int r = 0; r < 4; ++r) xv[r] = *(const float4*)(S + (rowB + r) * DIM + kc);
#pragma unroll
    for (int c = 0; c < 4; ++c) wv[c] = *(const float4*)(W + (size_t)(colB + c) * DIM + kc);
#pragma unroll
    for (int r = 0; r < 4; ++r)
#pragma unroll
      for (int c = 0; c < 4; ++c)
        acc[r][c] += xv[r].x * wv[c].x + xv[r].y * wv[c].y + xv[r].z * wv[c].z + xv[r].w * wv[c].w;
  }
}

__device__ __forceinline__ void layer_lds(const float* Sin, float* Sout,
                                          const float* __restrict__ W, const float* __restrict__ B,
                                          bool relu, int colB, int rowB) {
  float acc[4][4];
#pragma unroll
  for (int r = 0; r < 4; ++r)
#pragma unroll
    for (int cc = 0; cc < 4; ++cc) acc[r][cc] = B[colB + cc];
  tile_gemm(Sin, W, colB, rowB, acc);
#pragma unroll
  for (int r = 0; r < 4; ++r) {
    float4 v;
    v.x = acc[r][0]; v.y = acc[r][1]; v.z = acc[r][2]; v.w = acc[r][3];
    if (relu) { v.x = fmaxf(v.x, 0.f); v.y = fmaxf(v.y, 0.f); v.z = fmaxf(v.z, 0.f); v.w = fmaxf(v.w, 0.f); }
    *(float4*)&Sout[(rowB + r) * DIM + colB] = v;
  }
  __syncthreads();
}

__global__ __launch_bounds__(256) void vote_kernel(
    const float* __restrict__ X, int M,
    const float* __restrict__ W1, const float* __restrict__ b1,
    const float* __restrict__ W2, const float* __restrict__ b2,
    const float* __restrict__ W3, const float* __restrict__ b3,
    float* __restrict__ out) {
  __shared__ float Xs[32 * DIM];
  __shared__ float Ys[32 * DIM];
  int tid = threadIdx.x;
  int rb = blockIdx.x * 32;
  int mrows = M - rb; if (mrows > 32) mrows = 32;
  {
    const float4* src = (const float4*)(X + (size_t)rb * DIM);
    float4* dst = (float4*)Xs;
    int nf4 = mrows * (DIM / 4);
    for (int t = tid; t < 32 * (DIM / 4); t += 256) {
      float4 v;
      if (t < nf4) v = src[t];
      else { v.x = v.y = v.z = v.w = 0.f; }
      dst[t] = v;
    }
  }
  __syncthreads();
  int tx = tid & 31, ty = tid >> 5;
  int colB = tx * 4, rowB = ty * 4;
  layer_lds(Xs, Ys, W1, b1, true, colB, rowB);
  layer_lds(Ys, Xs, W2, b2, true, colB, rowB);
  if (tid < 32) {
    int gr = rb + tid;
    if (gr < M) {
      float s = b3[0];
      for (int k = 0; k < DIM; ++k) s += Xs[tid * DIM + k] * W3[k];
      out[gr] = s;
    }
  }
}

extern "C" void kernel_launch(void* const* d_in, const int* in_sizes, int n_in,
                              void* d_out, int out_size, void* d_ws, size_t ws_size,
                              hipStream_t stream) {
  const float* adj    = (const float*)d_in[0];
  const int*   values = (const int*)d_in[1];
  const int N       = in_sizes[1];                  // 9000
  const int n_nodes = in_sizes[0] / N;              // 8000
  const int n_vars  = N - n_nodes;                  // 1000

  const float* true_W  = (const float*)d_in[3];
  const float* true_b  = (const float*)d_in[4];
  const float* false_W = (const float*)d_in[5];
  const float* false_b = (const float*)d_in[6];
  const float* cm_W1 = (const float*)d_in[7];
  const float* cm_b1 = (const float*)d_in[8];
  const float* cm_W2 = (const float*)d_in[9];
  const float* cm_b2 = (const float*)d_in[10];
  const float* cm_W3 = (const float*)d_in[11];
  const float* cm_b3 = (const float*)d_in[12];
  const float* pm_W1 = (const float*)d_in[13];
  const float* pm_b1 = (const float*)d_in[14];
  const float* pm_W2 = (const float*)d_in[15];
  const float* pm_b2 = (const float*)d_in[16];
  const float* pm_W3 = (const float*)d_in[17];
  const float* pm_b3 = (const float*)d_in[18];
  const float* vv_W1 = (const float*)d_in[19];
  const float* vv_b1 = (const float*)d_in[20];
  const float* vv_W2 = (const float*)d_in[21];
  const float* vv_b2 = (const float*)d_in[22];
  const float* vv_W3 = (const float*)d_in[23];
  const float* vv_b3 = (const float*)d_in[24];
  const float* vu_Wih = (const float*)d_in[25];
  const float* vu_Whh = (const float*)d_in[26];
  const float* vu_bih = (const float*)d_in[27];
  const float* vu_bhh = (const float*)d_in[28];
  const float* nu_Wih = (const float*)d_in[29];
  const float* nu_Whh = (const float*)d_in[30];
  const float* nu_bih = (const float*)d_in[31];
  const float* nu_bhh = (const float*)d_in[32];

  uintptr_t p = (uintptr_t)d_ws;
  auto take = [&](size_t bytes) -> void* {
    uintptr_t cur = (p + 255) & ~(uintptr_t)255;
    p = cur + bytes;
    return (void*)cur;
  };
  size_t vs = (size_t)N * DIM;  // one va buffer, elements
  float* h   = (float*)take((size_t)N * DIM * sizeof(float));
  _Float16* va1 = (_Float16*)take(vs * RING * sizeof(_Float16));
  _Float16* va2 = (_Float16*)take(vs * RING * sizeof(_Float16));
  int* row_ptr = (int*)take((size_t)(n_nodes + 1) * sizeof(int));
  int* col_ptr = (int*)take((size_t)(N + 1) * sizeof(int));
  int* cnts    = (int*)take((size_t)(n_nodes + N) * sizeof(int));
  int* row_cnt = cnts;
  int* col_cnt = cnts + n_nodes;
  int* col_cur = (int*)take((size_t)N * sizeof(int));
  int* col_idx = (int*)take((size_t)NNZ_CAP * sizeof(int));
  int* row_idx = (int*)take((size_t)NNZ_CAP * sizeof(int));

  size_t tot_pack = (size_t)6 * SZ128 + (size_t)4 * SZ512;
  _Float16* packh = (_Float16*)take(tot_pack * sizeof(_Float16));
  float* vu_b = (float*)take(512 * sizeof(float));
  float* nu_b = (float*)take(512 * sizeof(float));
  unsigned* bar = (unsigned*)take((size_t)(NB + 2) * 16 * sizeof(unsigned));

  hipMemsetAsync(cnts, 0, (size_t)(n_nodes + N) * sizeof(int), stream);
  hipMemsetAsync(bar, 0, (size_t)(NB + 2) * 16 * sizeof(unsigned), stream);

  int cols4 = (N + 3) / 4;
  dim3 cgrid(n_nodes, (cols4 + 255) / 256);
  count_nz_kernel<<<cgrid, 256, 0, stream>>>(adj, row_cnt, col_cnt, N);
  scan_kernel<<<1, 256, 0, stream>>>(row_cnt, row_ptr, n_nodes);
  scan_kernel<<<1, 256, 0, stream>>>(col_cnt, col_ptr, N);
  copy_int_kernel<<<(N + 255) / 256, 256, 0, stream>>>(col_ptr, col_cur, N);
  fill_csr_csc_kernel<<<n_nodes, 64, 0, stream>>>(adj, row_ptr, col_idx, col_cur, row_idx, N);

  auto pack = [&](const float* src, int out_dim, size_t o) {
    pack_w_kernel<<<(out_dim * DIM + 255) / 256, 256, 0, stream>>>(src, out_dim, packh + o);
  };
  pack(cm_W1, DIM, O_CM1); pack(cm_W2, DIM, O_CM2); pack(cm_W3, DIM, O_CM3);
  pack(pm_W1, DIM, O_PM1); pack(pm_W2, DIM, O_PM2); pack(pm_W3, DIM, O_PM3);
  pack(vu_Wih, 4 * DIM, O_VUX); pack(vu_Whh, 4 * DIM, O_VUH);
  pack(nu_Wih, 4 * DIM, O_NUX); pack(nu_Whh, 4 * DIM, O_NUH);
  pack_bias_kernel<<<2, 256, 0, stream>>>(vu_bih, vu_bhh, vu_b, 512);
  pack_bias_kernel<<<2, 256, 0, stream>>>(nu_bih, nu_bhh, nu_b, 512);

  // persistent kernel: NB blocks, forced 1/CU by LDS footprint -> all co-resident
  int ns1 = (n_nodes + NB * 16 - 1) / (NB * 16);  // node-row subtiles (2 for 8000/250)
  if (ns1 <= 2) {
    persist_kernel<2><<<NB, 512, 0, stream>>>(
        row_ptr, col_idx, col_ptr, row_idx, values, true_W, true_b, false_W, false_b,
        packh, vu_b, nu_b, cm_b1, cm_b2, cm_b3, pm_b1, pm_b2, pm_b3,
        va1, va2, vs, h, bar, n_nodes, N, NB);
  } else {
    persist_kernel<3><<<NB, 512, 0, stream>>>(
        row_ptr, col_idx, col_ptr, row_idx, values, true_W, true_b, false_W, false_b,
        packh, vu_b, nu_b, cm_b1, cm_b2, cm_b3, pm_b1, pm_b2, pm_b3,
        va1, va2, vs, h, bar, n_nodes, N, NB);
  }

  vote_kernel<<<(n_vars + 31) / 32, 256, 0, stream>>>(h + (size_t)n_nodes * DIM, n_vars,
      vv_W1, vv_b1, vv_W2, vv_b2, vv_W3, vv_b3, (float*)d_out);
}

// Round 8
// 10206.654 us; speedup vs baseline: 1.2449x; 1.0103x over previous
//
#include <hip/hip_runtime.h>
#include <cstddef>
#include <cstdint>

#define DIM 128
#define NROUNDS 120
#define NNZ_CAP (1 << 20)
#define NB 250  // persistent grid: 250 blocks, forced 1/CU via LDS footprint (<=256 CUs)
#define IDXCAP 3584  // LDS nz-index pool (ints); per-block avg ~2050, tail ~2600
#define RING 6  // va address-rotation depth: slot reused after 12 phases >> L2 lifetime

typedef _Float16 half8 __attribute__((ext_vector_type(8)));
typedef float f32x4 __attribute__((ext_vector_type(4)));
typedef unsigned long long u64;

__device__ __forceinline__ float sigf(float x) { return 1.f / (1.f + __expf(-x)); }
__device__ __forceinline__ float tanh_fast(float x) { return 2.f / (1.f + __expf(-2.f * x)) - 1.f; }

// ---- va WRITES: 16B write-through stores (sc0 sc1 -> bypass L1/L2 to the coherence
// point, full-line coalesced: 16 lanes cover one 256B row). va READS: plain CACHED
// loads -- correct WITHOUT fences via ring address-rotation (slot re-read only after
// 12 phases of L2 churn). Drain stores with vmcnt(0) before barrier signal. ----
__device__ __forceinline__ void st16(void* a, half8 v) {
  asm volatile("global_store_dwordx4 %0, %1, off sc0 sc1" :: "v"(a), "v"(v) : "memory");
}

// ---------------- sparse build ----------------
__global__ void count_nz_kernel(const float* __restrict__ adj, int* __restrict__ row_cnt,
                                int* __restrict__ col_cnt, int ncols) {
  int i = blockIdx.x;
  int t4 = blockIdx.y * blockDim.x + threadIdx.x;
  int j0 = t4 * 4;
  int c = 0;
  if (j0 < ncols) {
    if ((ncols & 3) == 0) {
      float4 v = *(const float4*)(adj + (size_t)i * ncols + j0);
      if (v.x != 0.f) { atomicAdd(&col_cnt[j0 + 0], 1); ++c; }
      if (v.y != 0.f) { atomicAdd(&col_cnt[j0 + 1], 1); ++c; }
      if (v.z != 0.f) { atomicAdd(&col_cnt[j0 + 2], 1); ++c; }
      if (v.w != 0.f) { atomicAdd(&col_cnt[j0 + 3], 1); ++c; }
    } else {
      for (int e = 0; e < 4 && j0 + e < ncols; ++e)
        if (adj[(size_t)i * ncols + j0 + e] != 0.f) { atomicAdd(&col_cnt[j0 + e], 1); ++c; }
    }
  }
  for (int off = 32; off; off >>= 1) c += __shfl_down(c, off, 64);
  if ((threadIdx.x & 63) == 0 && c) atomicAdd(&row_cnt[i], c);
}

__global__ void scan_kernel(const int* __restrict__ cnt, int* __restrict__ ptr, int n) {
  __shared__ int sdata[256];
  int t = threadIdx.x;
  int per = (n + 255) / 256;
  int beg = t * per;
  int end = beg + per; if (end > n) end = n;
  int local = 0;
  for (int i = beg; i < end; ++i) local += cnt[i];
  sdata[t] = local;
  __syncthreads();
  for (int off = 1; off < 256; off <<= 1) {
    int v = (t >= off) ? sdata[t - off] : 0;
    __syncthreads();
    sdata[t] += v;
    __syncthreads();
  }
  int run = sdata[t] - local;
  for (int i = beg; i < end; ++i) { ptr[i] = run; run += cnt[i]; }
  if (t == 255) ptr[n] = sdata[255];
}

__global__ void copy_int_kernel(const int* __restrict__ a, int* __restrict__ b, int n) {
  int i = blockIdx.x * 256 + threadIdx.x;
  if (i < n) b[i] = a[i];
}

// CSR fill (deterministic order) + CSC fill via atomic column cursors
__global__ __launch_bounds__(64) void fill_csr_csc_kernel(const float* __restrict__ adj,
                                                          const int* __restrict__ row_ptr,
                                                          int* __restrict__ col_idx,
                                                          int* __restrict__ col_cur,
                                                          int* __restrict__ row_idx, int ncols) {
  int row = blockIdx.x;
  int lane = threadIdx.x;
  int base = row_ptr[row];
  int cursor = 0;
  const float* arow = adj + (size_t)row * ncols;
  for (int j0 = 0; j0 < ncols; j0 += 64) {
    int j = j0 + lane;
    bool nz = (j < ncols) && (arow[j] != 0.f);
    u64 m = __ballot(nz);
    int pre = __popcll(m & ((1ull << lane) - 1));
    if (nz) {
      col_idx[base + cursor + pre] = j;
      int t = atomicAdd(&col_cur[j], 1);
      row_idx[t] = row;
    }
    cursor += __popcll(m);
  }
}

// ---------------- weight packing: MFMA 16x16x32 B-fragment order (f16 only) ----------------
__global__ void pack_w_kernel(const float* __restrict__ src, int out_dim,
                              _Float16* __restrict__ dh) {
  int idx = blockIdx.x * 256 + threadIdx.x;
  if (idx >= out_dim * DIM) return;
  int n = idx >> 7, k = idx & 127;
  _Float16 hi = (_Float16)src[idx];
  int nt = n >> 4, ks = k >> 5;
  int L = ((k >> 3) & 3) * 16 + (n & 15);
  int j = k & 7;
  dh[((nt * 4 + ks) * 64 + L) * 8 + j] = hi;
}

__global__ void pack_bias_kernel(const float* __restrict__ a, const float* __restrict__ b,
                                 float* __restrict__ o, int n) {
  int i = blockIdx.x * 256 + threadIdx.x;
  if (i < n) o[i] = a[i] + b[i];
}

// ---------------- LDS swizzle (rows x 128, 8-chunk XOR) ----------------
__device__ __forceinline__ int sw_idx(int m, int k) {
  return (m << 7) + (((((k >> 3) ^ (m & 15))) << 3) | (k & 7));
}

// L2-warm touch: independent line loads covering w[0..n) at 128B stride
__device__ __forceinline__ float touch(const _Float16* __restrict__ w, int n, int tid) {
  float t = 0.f;
  for (int i = tid * 64; i < n; i += 512 * 64) t += (float)w[i];
  return t;
}

// per-XCD cooperative va warm: blocks sharing blockIdx%8 (presumed XCD round-robin)
// partition the buffer; one streaming fetch per XCD turns the scattered gather into
// L2 hits. Pure prefetch -- wrong mapping degrades perf, never correctness.
__device__ __forceinline__ float warm_va(const _Float16* __restrict__ v, size_t elems,
                                         int b, int nblocks, int tid) {
  int res = b & 7;
  int nsl = (nblocks - 1 - res) / 8 + 1;
  int sl = b >> 3;
  size_t beg = elems * (size_t)sl / nsl, end = elems * (size_t)(sl + 1) / nsl;
  float t = 0.f;
  for (size_t i = beg + (size_t)tid * 32; i < end; i += 512 * 32) t += (float)v[i];
  return t;
}

// binary-SpMM gather with LDS-cached nz byte-offsets; va via CACHED half8 loads
template <int NS>
__device__ __forceinline__ void gather_lds(const int* Sidx, const int* lofs, const int* lcnt,
                                           int mbase,
                                           const int* __restrict__ gptr,
                                           const int* __restrict__ gidx,
                                           const _Float16* __restrict__ va, int rowlim,
                                           int b, int nb, _Float16* Xh, _Float16* Xl, int tid) {
  int seg = tid & 15;
  const char* vab = (const char*)va + seg * 16;
  for (int r = tid >> 4; r < NS * 16; r += 32) {
    float a[8];
#pragma unroll
    for (int e = 0; e < 8; ++e) a[e] = 0.f;
    int lo = lofs[mbase + r], c = lcnt[mbase + r];
    if (lo >= 0) {
      const int* ip = Sidx + lo;
      int p = 0;
      for (; p + 8 <= c; p += 8) {
        half8 v0 = *(const half8*)(vab + ip[p]);
        half8 v1 = *(const half8*)(vab + ip[p + 1]);
        half8 v2 = *(const half8*)(vab + ip[p + 2]);
        half8 v3 = *(const half8*)(vab + ip[p + 3]);
        half8 v4 = *(const half8*)(vab + ip[p + 4]);
        half8 v5 = *(const half8*)(vab + ip[p + 5]);
        half8 v6 = *(const half8*)(vab + ip[p + 6]);
        half8 v7 = *(const half8*)(vab + ip[p + 7]);
#pragma unroll
        for (int e = 0; e < 8; ++e)
          a[e] += (((float)v0[e] + (float)v1[e]) + ((float)v2[e] + (float)v3[e])) +
                  (((float)v4[e] + (float)v5[e]) + ((float)v6[e] + (float)v7[e]));
      }
      for (; p + 2 <= c; p += 2) {
        half8 v0 = *(const half8*)(vab + ip[p]);
        half8 v1 = *(const half8*)(vab + ip[p + 1]);
#pragma unroll
        for (int e = 0; e < 8; ++e) a[e] += (float)v0[e] + (float)v1[e];
      }
      if (p < c) {
        half8 v = *(const half8*)(vab + ip[p]);
#pragma unroll
        for (int e = 0; e < 8; ++e) a[e] += (float)v[e];
      }
    } else {
      int row = b + r * nb;
      if (row < rowlim) {
        int s0 = gptr[row], e_ = gptr[row + 1];
        for (int p = s0; p < e_; ++p) {
          half8 v = *(const half8*)(va + (size_t)gidx[p] * DIM + seg * 8);
#pragma unroll
          for (int e = 0; e < 8; ++e) a[e] += (float)v[e];
        }
      }
    }
    int aoff = sw_idx(r, seg * 8);
#pragma unroll
    for (int e = 0; e < 8; ++e) {
      _Float16 hi = (_Float16)a[e];
      Xh[aoff + e] = hi;
      Xl[aoff + e] = (_Float16)(a[e] - (float)hi);
    }
  }
}

// split-A x f16-B: 2 MFMAs per product
__device__ __forceinline__ void mfma2(f32x4& acc, half8 ah, half8 al, half8 bh) {
  acc = __builtin_amdgcn_mfma_f32_16x16x32_f16(ah, bh, acc, 0, 0, 0);
  acc = __builtin_amdgcn_mfma_f32_16x16x32_f16(al, bh, acc, 0, 0, 0);
}

// one MLP layer: NS 16-row subtiles, 8 waves; wave w owns col tile w (16 cols)
template <int NS>
__device__ __forceinline__ void mlp_layer_t(const _Float16* Ah_, const _Float16* Al_,
                                            const _Float16* __restrict__ Wh,
                                            const float* __restrict__ B,
                                            _Float16* Dh, _Float16* Dl, int tid) {
  int lane = tid & 63, w = tid >> 6;
  int m16 = lane & 15, quad = lane >> 4;
  float bv = B[w * 16 + m16];
  f32x4 acc[NS];
#pragma unroll
  for (int s = 0; s < NS; ++s) acc[s] = (f32x4){bv, bv, bv, bv};
#pragma unroll
  for (int ks = 0; ks < 4; ++ks) {
    int boff = ((w * 4 + ks) * 64 + lane) * 8;
    half8 bh = *(const half8*)(Wh + boff);
#pragma unroll
    for (int s = 0; s < NS; ++s) {
      int a_off = sw_idx(s * 16 + m16, ks * 32 + quad * 8);
      mfma2(acc[s], *(const half8*)(Ah_ + a_off), *(const half8*)(Al_ + a_off), bh);
    }
  }
#pragma unroll
  for (int s = 0; s < NS; ++s)
#pragma unroll
    for (int reg = 0; reg < 4; ++reg) {
      int rl = s * 16 + quad * 4 + reg;
      int col = w * 16 + m16;
      float x = fmaxf(acc[s][reg], 0.f);
      _Float16 hi = (_Float16)x;
      int a = sw_idx(rl, col);
      Dh[a] = hi;
      Dl[a] = (_Float16)(x - (float)hi);
    }
  __syncthreads();
}

// 3-layer MLP: input Ah/Al preserved; T1/T2 scratch; final output staged in T1h then
// written as coalesced 16B sc0sc1 stores (16 lanes = one 256B va row)
template <int NS>
__device__ __forceinline__ void mlp_pers(const _Float16* Ah, const _Float16* Al,
                                         _Float16* T1h, _Float16* T1l,
                                         _Float16* T2h, _Float16* T2l,
                                         const _Float16* __restrict__ W1h, const float* __restrict__ b1,
                                         const _Float16* __restrict__ W2h, const float* __restrict__ b2,
                                         const _Float16* __restrict__ W3h, const float* __restrict__ b3,
                                         _Float16* __restrict__ out, int rowlim, int b, int nb,
                                         int tid) {
  mlp_layer_t<NS>(Ah, Al, W1h, b1, T1h, T1l, tid);
  mlp_layer_t<NS>(T1h, T1l, W2h, b2, T2h, T2l, tid);
  int lane = tid & 63, w = tid >> 6;
  int m16 = lane & 15, quad = lane >> 4;
  float bv = b3[w * 16 + m16];
  f32x4 acc[NS];
#pragma unroll
  for (int s = 0; s < NS; ++s) acc[s] = (f32x4){bv, bv, bv, bv};
#pragma unroll
  for (int ks = 0; ks < 4; ++ks) {
    int boff = ((w * 4 + ks) * 64 + lane) * 8;
    half8 bh = *(const half8*)(W3h + boff);
#pragma unroll
    for (int s = 0; s < NS; ++s) {
      int a_off = sw_idx(s * 16 + m16, ks * 32 + quad * 8);
      mfma2(acc[s], *(const half8*)(T2h + a_off), *(const half8*)(T2l + a_off), bh);
    }
  }
  // stage rows (linear [slot][128]) -- T1 is free after layer 2's trailing sync
#pragma unroll
  for (int s = 0; s < NS; ++s)
#pragma unroll
    for (int reg = 0; reg < 4; ++reg) {
      int rl = s * 16 + quad * 4 + reg;
      T1h[rl * DIM + w * 16 + m16] = (_Float16)acc[s][reg];
    }
  __syncthreads();
  {
    int seg = tid & 15;
    for (int r = tid >> 4; r < NS * 16; r += 32) {
      int row = b + r * nb;
      if (row < rowlim) {
        half8 v = *(const half8*)(T1h + r * DIM + seg * 8);
        st16(out + (size_t)row * DIM + seg * 8, v);
      }
    }
  }
}

// LSTM gate matmuls with A-fragment hoisting
template <int NS>
__device__ __forceinline__ void lstm_pers(const _Float16* Hh, const _Float16* Hl,
                                          const _Float16* Xh, const _Float16* Xl,
                                          const _Float16* __restrict__ Wxh,
                                          const _Float16* __restrict__ Whh_,
                                          const float* __restrict__ bcomb, int tid,
                                          f32x4 (&acc)[NS][4]) {
  int lane = tid & 63, w = tid >> 6;
  int m16 = lane & 15, quad = lane >> 4;
#pragma unroll
  for (int g = 0; g < 4; ++g) {
    float bv = bcomb[g * 128 + w * 16 + m16];
#pragma unroll
    for (int s = 0; s < NS; ++s) acc[s][g] = (f32x4){bv, bv, bv, bv};
  }
#pragma unroll
  for (int ks = 0; ks < 4; ++ks) {
    half8 ah[NS], al[NS];
#pragma unroll
    for (int s = 0; s < NS; ++s) {
      int a_off = sw_idx(s * 16 + m16, ks * 32 + quad * 8);
      ah[s] = *(const half8*)(Hh + a_off);
      al[s] = *(const half8*)(Hl + a_off);
    }
#pragma unroll
    for (int g = 0; g < 4; ++g) {
      int boff = (((g * 8 + w) * 4 + ks) * 64 + lane) * 8;
      half8 bh = *(const half8*)(Whh_ + boff);
#pragma unroll
      for (int s = 0; s < NS; ++s) mfma2(acc[s][g], ah[s], al[s], bh);
    }
#pragma unroll
    for (int s = 0; s < NS; ++s) {
      int a_off = sw_idx(s * 16 + m16, ks * 32 + quad * 8);
      ah[s] = *(const half8*)(Xh + a_off);
      al[s] = *(const half8*)(Xl + a_off);
    }
#pragma unroll
    for (int g = 0; g < 4; ++g) {
      int boff = (((g * 8 + w) * 4 + ks) * 64 + lane) * 8;
      half8 bh = *(const half8*)(Wxh + boff);
#pragma unroll
      for (int s = 0; s < NS; ++s) mfma2(acc[s][g], ah[s], al[s], bh);
    }
  }
}

// ---------------- fence-free device barrier ----------------
// va stores are write-through (sc0 sc1): drain via vmcnt before signaling; no cache
// ops. Per-block arrival slots; block 0 polls, publishes 'go'. Bounded spins.
#define GO_IDX (NB * 16)
__device__ __forceinline__ void gbar(unsigned* __restrict__ bar, int nblocks, unsigned ep,
                                     int b, int tid) {
  asm volatile("s_waitcnt vmcnt(0)" ::: "memory");  // our write-through stores are at L3
  __syncthreads();
  if (b == 0) {
    if (tid < 64) {
      int guard = 0;
      for (;;) {
        int ok = 1;
        for (int s = 1 + tid; s < nblocks; s += 64) {
          unsigned v = __hip_atomic_load(&bar[s * 16], __ATOMIC_RELAXED, __HIP_MEMORY_SCOPE_AGENT);
          ok &= (int)(v >= ep);
        }
        if (__all(ok)) break;
        __builtin_amdgcn_s_sleep(2);
        if (++guard > (1 << 15)) break;  // safety valve
      }
      if (tid == 0)
        __hip_atomic_store(&bar[GO_IDX], ep, __ATOMIC_RELAXED, __HIP_MEMORY_SCOPE_AGENT);
    }
  } else if (tid == 0) {
    __hip_atomic_store(&bar[b * 16], ep, __ATOMIC_RELAXED, __HIP_MEMORY_SCOPE_AGENT);
    int guard = 0;
    while (__hip_atomic_load(&bar[GO_IDX], __ATOMIC_RELAXED, __HIP_MEMORY_SCOPE_AGENT) < ep) {
      __builtin_amdgcn_s_sleep(8);
      if (++guard > (1 << 17)) break;  // safety valve
    }
  }
  __syncthreads();
}

#define SZ128 (DIM * DIM)
#define SZ512 (4 * DIM * DIM)
#define O_CM1 0
#define O_CM2 (SZ128)
#define O_CM3 (2 * SZ128)
#define O_PM1 (3 * SZ128)
#define O_PM2 (4 * SZ128)
#define O_PM3 (5 * SZ128)
#define O_VUX ((size_t)6 * SZ128)
#define O_VUH ((size_t)6 * SZ128 + SZ512)
#define O_NUX ((size_t)6 * SZ128 + 2 * SZ512)
#define O_NUH ((size_t)6 * SZ128 + 3 * SZ512)

// LDS: 6 x 6912 x 2B (split-f16 tiles) + idx pool + meta = ~98KB -> 1 block/CU.
#define LSLOT (3 * 2048 + 768)

// ---------------- persistent kernel: all 120 rounds, h in LDS, c in VGPRs ----------------
template <int NS1>
__global__ __launch_bounds__(512, 2) void persist_kernel(
    const int* __restrict__ row_ptr, const int* __restrict__ col_idx,
    const int* __restrict__ col_ptr, const int* __restrict__ row_idx,
    const int* __restrict__ values, const float* __restrict__ tW, const float* __restrict__ tb,
    const float* __restrict__ fW, const float* __restrict__ fb,
    const _Float16* __restrict__ packh,
    const float* __restrict__ vu_b, const float* __restrict__ nu_b,
    const float* __restrict__ cm_b1, const float* __restrict__ cm_b2,
    const float* __restrict__ cm_b3, const float* __restrict__ pm_b1,
    const float* __restrict__ pm_b2, const float* __restrict__ pm_b3,
    _Float16* __restrict__ va1, _Float16* __restrict__ va2, size_t vstride,
    float* __restrict__ hout, unsigned* __restrict__ bar,
    int n_nodes, int N, int nblocks) {
  __shared__ _Float16 Hh[LSLOT], Hl[LSLOT], Xh[LSLOT], Xl[LSLOT], T2h[LSLOT], T2l[LSLOT];
  __shared__ int Sidx[IDXCAP];
  __shared__ int lofs[96], lcnt[96], gstb[96];
  int tid = threadIdx.x, b = blockIdx.x;
  int lane = tid & 63, w = tid >> 6, m16 = lane & 15, quad = lane >> 4;

  const _Float16* CM1 = packh + O_CM1;
  const _Float16* CM2 = packh + O_CM2;
  const _Float16* CM3 = packh + O_CM3;
  const _Float16* PM1 = packh + O_PM1;
  const _Float16* PM2 = packh + O_PM2;
  const _Float16* PM3 = packh + O_PM3;
  const _Float16* VUX = packh + O_VUX;
  const _Float16* VUH = packh + O_VUH;
  const _Float16* NUX = packh + O_NUX;
  const _Float16* NUH = packh + O_NUH;

  // persistent cell state in registers; persistent h (split f16) in LDS
  float cold[3][4];
#pragma unroll
  for (int s = 0; s < 3; ++s)
#pragma unroll
    for (int reg = 0; reg < 4; ++reg) {
      cold[s][reg] = 0.f;
      int rl = s * 16 + quad * 4 + reg;
      int row = b + rl * nblocks;
      int col = w * 16 + m16;
      float hv = 0.f;
      if (row < N) hv = (values[row] == 1) ? (tW[col] + tb[col]) : (fW[col] + fb[col]);
      int a = sw_idx(rl, col);
      _Float16 hi = (_Float16)hv;
      Hh[a] = hi;
      Hl[a] = (_Float16)(hv - (float)hi);
    }

  // ---- stage this block's static nz lists into LDS (once) ----
  // slots [0,48): phase-1 CSR rows; [48,96): phase-2 CSC rows. Stored as byte offsets.
  if (tid < 96) {
    int s = tid, row, c = 0, gs = 0;
    if (s < 48) {
      row = b + s * nblocks;
      if (row < n_nodes) { gs = row_ptr[row]; c = row_ptr[row + 1] - gs; }
    } else {
      row = b + (s - 48) * nblocks;
      if (row < N) { gs = col_ptr[row]; c = col_ptr[row + 1] - gs; }
    }
    gstb[s] = gs;
    lcnt[s] = c;
  }
  __syncthreads();
  if (tid == 0) {
    int cur = 0;
    for (int s = 0; s < 96; ++s) {
      int c = lcnt[s];
      if (c > 0 && cur + c <= IDXCAP) { lofs[s] = cur; cur += c; }
      else if (c > 0) lofs[s] = -1;   // overflow: global fallback for this row
      else lofs[s] = 0;
    }
  }
  __syncthreads();
  for (int s = 0; s < 96; ++s) {
    int c = lcnt[s], lo = lofs[s];
    if (lo < 0 || c == 0) continue;
    int gs = gstb[s];
    const int* src = (s < 48) ? col_idx : row_idx;
    for (int i = tid; i < c; i += 512) Sidx[lo + i] = src[gs + i] << 8;  // *256B
  }
  __syncthreads();

  unsigned ep = 0;
  // phase 0: va1[slot 0] = cm_mlp(h0) over all rows
  {
    float tpf = touch(CM1, DIM * DIM, tid) + touch(CM2, DIM * DIM, tid) +
                touch(CM3, DIM * DIM, tid);
    asm volatile("" :: "v"(tpf));
  }
  mlp_pers<3>(Hh, Hl, Xh, Xl, T2h, T2l, CM1, cm_b1, CM2, cm_b2, CM3, cm_b3,
              va1, N, b, nblocks, tid);
  gbar(bar, nblocks, ++ep, b, tid);

  for (int r = 0; r < NROUNDS; ++r) {
    // ring slots: this round reads va1[r%R], writes va2[r%R]; phase 2 writes va1[(r+1)%R]
    const _Float16* va1r = va1 + (size_t)(r % RING) * vstride;
    _Float16* va2w = va2 + (size_t)(r % RING) * vstride;
    _Float16* va1w = va1 + (size_t)((r + 1) % RING) * vstride;

    // ---- phase 1: vu-LSTM(CSR gather va1) on node rows + pm-MLP -> va2 ----
    {
      float tpf = warm_va(va1r, (size_t)N * DIM, b, nblocks, tid);
      gather_lds<NS1>(Sidx, lofs, lcnt, 0, row_ptr, col_idx, va1r, n_nodes, b, nblocks,
                      Xh, Xl, tid);
      tpf += touch(VUX, 4 * DIM * DIM, tid) + touch(VUH, 4 * DIM * DIM, tid) +
             touch(PM1, DIM * DIM, tid) + touch(PM2, DIM * DIM, tid) +
             touch(PM3, DIM * DIM, tid);
      asm volatile("" :: "v"(tpf));
    }
    __syncthreads();
    {
      f32x4 acc[NS1][4];
      lstm_pers<NS1>(Hh, Hl, Xh, Xl, VUX, VUH, vu_b, tid, acc);
      __syncthreads();  // all waves done reading Hh/Xh before h overwrite
#pragma unroll
      for (int s = 0; s < NS1; ++s)
#pragma unroll
        for (int reg = 0; reg < 4; ++reg) {
          int rl = s * 16 + quad * 4 + reg;
          int row = b + rl * nblocks;
          if (row < n_nodes) {
            float iv = sigf(acc[s][0][reg]);
            float fv = sigf(acc[s][1][reg]);
            float gv = tanh_fast(acc[s][2][reg]);
            float ov = sigf(acc[s][3][reg]);
            float cn = fv * cold[s][reg] + iv * gv;
            cold[s][reg] = cn;
            float hn = ov * tanh_fast(cn);
            int a = sw_idx(rl, w * 16 + m16);
            _Float16 hi = (_Float16)hn;
            Hh[a] = hi;
            Hl[a] = (_Float16)(hn - (float)hi);
          }
        }
    }
    __syncthreads();
    mlp_pers<NS1>(Hh, Hl, Xh, Xl, T2h, T2l, PM1, pm_b1, PM2, pm_b2, PM3, pm_b3,
                  va2w, n_nodes, b, nblocks, tid);
    gbar(bar, nblocks, ++ep, b, tid);

    // ---- phase 2: nu-LSTM(CSC gather va2) on all rows (+ cm-MLP -> va1 unless last) ----
    bool last = (r == NROUNDS - 1);
    {
      float tpf = warm_va(va2w, (size_t)n_nodes * DIM, b, nblocks, tid);
      gather_lds<3>(Sidx, lofs, lcnt, 48, col_ptr, row_idx, va2w, N, b, nblocks, Xh, Xl, tid);
      tpf += touch(NUX, 4 * DIM * DIM, tid) + touch(NUH, 4 * DIM * DIM, tid) +
             touch(CM1, DIM * DIM, tid) + touch(CM2, DIM * DIM, tid) +
             touch(CM3, DIM * DIM, tid);
      asm volatile("" :: "v"(tpf));
    }
    __syncthreads();
    {
      f32x4 acc[3][4];
      lstm_pers<3>(Hh, Hl, Xh, Xl, NUX, NUH, nu_b, tid, acc);
      __syncthreads();
#pragma unroll
      for (int s = 0; s < 3; ++s)
#pragma unroll
        for (int reg = 0; reg < 4; ++reg) {
          int rl = s * 16 + quad * 4 + reg;
          int row = b + rl * nblocks;
          if (row < N) {
            float iv = sigf(acc[s][0][reg]);
            float fv = sigf(acc[s][1][reg]);
            float gv = tanh_fast(acc[s][2][reg]);
            float ov = sigf(acc[s][3][reg]);
            float cn = fv * cold[s][reg] + iv * gv;
            cold[s][reg] = cn;
            float hn = ov * tanh_fast(cn);
            if (last) {
              hout[(size_t)row * DIM + (w * 16 + m16)] = hn;
            } else {
              int a = sw_idx(rl, w * 16 + m16);
              _Float16 hi = (_Float16)hn;
              Hh[a] = hi;
              Hl[a] = (_Float16)(hn - (float)hi);
            }
          }
        }
    }
    if (!last) {
      __syncthreads();
      mlp_pers<3>(Hh, Hl, Xh, Xl, T2h, T2l, CM1, cm_b1, CM2, cm_b2, CM3, cm_b3,
                  va1w, N, b, nblocks, tid);
      gbar(bar, nblocks, ++ep, b, tid);
    }
  }
}

// ---------------- final vote MLP (fp32, runs once) ----------------
__device__ __forceinline__ void tile_gemm(const float* S, const float* __restrict__ W,
                                          int colB, int rowB, float acc[4][4]) {
#pragma unroll 4
  for (int kc = 0; kc < DIM; kc += 4) {
    float4 xv[4], wv[4];
#pragma unroll
    for (int r = 0; r < 4; ++r) xv[r] = *(const float4*)(S + (rowB + r) * DIM + kc);
#pragma unroll
    for (int c = 0; c < 4; ++c) wv[c] = *(const float4*)(W + (size_t)(colB + c) * DIM + kc);
#pragma unroll
    for (int r = 0; r < 4; ++r)
#pragma unroll
      for (int c = 0; c < 4; ++c)
        acc[r][c] += xv[r].x * wv[c].x + xv[r].y * wv[c].y + xv[r].z * wv[c].z + xv[r].w * wv[c].w;
  }
}

__device__ __forceinline__ void layer_lds(const float* Sin, float* Sout,
                                          const float* __restrict__ W, const float* __restrict__ B,
                                          bool relu, int colB, int rowB) {
  float acc[4][4];
#pragma unroll
  for (int r = 0; r < 4; ++r)
#pragma unroll
    for (int cc = 0; cc < 4; ++cc) acc[r][cc] = B[colB + cc];
  tile_gemm(Sin, W, colB, rowB, acc);
#pragma unroll
  for (int r = 0; r < 4; ++r) {
    float4 v;
    v.x = acc[r][0]; v.y = acc[r][1]; v.z = acc[r][2]; v.w = acc[r][3];
    if (relu) { v.x = fmaxf(v.x, 0.f); v.y = fmaxf(v.y, 0.f); v.z = fmaxf(v.z, 0.f); v.w = fmaxf(v.w, 0.f); }
    *(float4*)&Sout[(rowB + r) * DIM + colB] = v;
  }
  __syncthreads();
}

__global__ __launch_bounds__(256) void vote_kernel(
    const float* __restrict__ X, int M,
    const float* __restrict__ W1, const float* __restrict__ b1,
    const float* __restrict__ W2, const float* __restrict__ b2,
    const float* __restrict__ W3, const float* __restrict__ b3,
    float* __restrict__ out) {
  __shared__ float Xs[32 * DIM];
  __shared__ float Ys[32 * DIM];
  int tid = threadIdx.x;
  int rb = blockIdx.x * 32;
  int mrows = M - rb; if (mrows > 32) mrows = 32;
  {
    const float4* src = (const float4*)(X + (size_t)rb * DIM);
    float4* dst = (float4*)Xs;
    int nf4 = mrows * (DIM / 4);
    for (int t = tid; t < 32 * (DIM / 4); t += 256) {
      float4 v;
      if (t < nf4) v = src[t];
      else { v.x = v.y = v.z = v.w = 0.f; }
      dst[t] = v;
    }
  }
  __syncthreads();
  int tx = tid & 31, ty = tid >> 5;
  int colB = tx * 4, rowB = ty * 4;
  layer_lds(Xs, Ys, W1, b1, true, colB, rowB);
  layer_lds(Ys, Xs, W2, b2, true, colB, rowB);
  if (tid < 32) {
    int gr = rb + tid;
    if (gr < M) {
      float s = b3[0];
      for (int k = 0; k < DIM; ++k) s += Xs[tid * DIM + k] * W3[k];
      out[gr] = s;
    }
  }
}

extern "C" void kernel_launch(void* const* d_in, const int* in_sizes, int n_in,
                              void* d_out, int out_size, void* d_ws, size_t ws_size,
                              hipStream_t stream) {
  const float* adj    = (const float*)d_in[0];
  const int*   values = (const int*)d_in[1];
  const int N       = in_sizes[1];                  // 9000
  const int n_nodes = in_sizes[0] / N;              // 8000
  const int n_vars  = N - n_nodes;                  // 1000

  const float* true_W  = (const float*)d_in[3];
  const float* true_b  = (const float*)d_in[4];
  const float* false_W = (const float*)d_in[5];
  const float* false_b = (const float*)d_in[6];
  const float* cm_W1 = (const float*)d_in[7];
  const float* cm_b1 = (const float*)d_in[8];
  const float* cm_W2 = (const float*)d_in[9];
  const float* cm_b2 = (const float*)d_in[10];
  const float* cm_W3 = (const float*)d_in[11];
  const float* cm_b3 = (const float*)d_in[12];
  const float* pm_W1 = (const float*)d_in[13];
  const float* pm_b1 = (const float*)d_in[14];
  const float* pm_W2 = (const float*)d_in[15];
  const float* pm_b2 = (const float*)d_in[16];
  const float* pm_W3 = (const float*)d_in[17];
  const float* pm_b3 = (const float*)d_in[18];
  const float* vv_W1 = (const float*)d_in[19];
  const float* vv_b1 = (const float*)d_in[20];
  const float* vv_W2 = (const float*)d_in[21];
  const float* vv_b2 = (const float*)d_in[22];
  const float* vv_W3 = (const float*)d_in[23];
  const float* vv_b3 = (const float*)d_in[24];
  const float* vu_Wih = (const float*)d_in[25];
  const float* vu_Whh = (const float*)d_in[26];
  const float* vu_bih = (const float*)d_in[27];
  const float* vu_bhh = (const float*)d_in[28];
  const float* nu_Wih = (const float*)d_in[29];
  const float* nu_Whh = (const float*)d_in[30];
  const float* nu_bih = (const float*)d_in[31];
  const float* nu_bhh = (const float*)d_in[32];

  uintptr_t p = (uintptr_t)d_ws;
  auto take = [&](size_t bytes) -> void* {
    uintptr_t cur = (p + 255) & ~(uintptr_t)255;
    p = cur + bytes;
    return (void*)cur;
  };
  size_t vs = (size_t)N * DIM;  // one va buffer, elements
  float* h   = (float*)take((size_t)N * DIM * sizeof(float));
  _Float16* va1 = (_Float16*)take(vs * RING * sizeof(_Float16));
  _Float16* va2 = (_Float16*)take(vs * RING * sizeof(_Float16));
  int* row_ptr = (int*)take((size_t)(n_nodes + 1) * sizeof(int));
  int* col_ptr = (int*)take((size_t)(N + 1) * sizeof(int));
  int* cnts    = (int*)take((size_t)(n_nodes + N) * sizeof(int));
  int* row_cnt = cnts;
  int* col_cnt = cnts + n_nodes;
  int* col_cur = (int*)take((size_t)N * sizeof(int));
  int* col_idx = (int*)take((size_t)NNZ_CAP * sizeof(int));
  int* row_idx = (int*)take((size_t)NNZ_CAP * sizeof(int));

  size_t tot_pack = (size_t)6 * SZ128 + (size_t)4 * SZ512;
  _Float16* packh = (_Float16*)take(tot_pack * sizeof(_Float16));
  float* vu_b = (float*)take(512 * sizeof(float));
  float* nu_b = (float*)take(512 * sizeof(float));
  unsigned* bar = (unsigned*)take((size_t)(NB + 2) * 16 * sizeof(unsigned));

  hipMemsetAsync(cnts, 0, (size_t)(n_nodes + N) * sizeof(int), stream);
  hipMemsetAsync(bar, 0, (size_t)(NB + 2) * 16 * sizeof(unsigned), stream);

  int cols4 = (N + 3) / 4;
  dim3 cgrid(n_nodes, (cols4 + 255) / 256);
  count_nz_kernel<<<cgrid, 256, 0, stream>>>(adj, row_cnt, col_cnt, N);
  scan_kernel<<<1, 256, 0, stream>>>(row_cnt, row_ptr, n_nodes);
  scan_kernel<<<1, 256, 0, stream>>>(col_cnt, col_ptr, N);
  copy_int_kernel<<<(N + 255) / 256, 256, 0, stream>>>(col_ptr, col_cur, N);
  fill_csr_csc_kernel<<<n_nodes, 64, 0, stream>>>(adj, row_ptr, col_idx, col_cur, row_idx, N);

  auto pack = [&](const float* src, int out_dim, size_t o) {
    pack_w_kernel<<<(out_dim * DIM + 255) / 256, 256, 0, stream>>>(src, out_dim, packh + o);
  };
  pack(cm_W1, DIM, O_CM1); pack(cm_W2, DIM, O_CM2); pack(cm_W3, DIM, O_CM3);
  pack(pm_W1, DIM, O_PM1); pack(pm_W2, DIM, O_PM2); pack(pm_W3, DIM, O_PM3);
  pack(vu_Wih, 4 * DIM, O_VUX); pack(vu_Whh, 4 * DIM, O_VUH);
  pack(nu_Wih, 4 * DIM, O_NUX); pack(nu_Whh, 4 * DIM, O_NUH);
  pack_bias_kernel<<<2, 256, 0, stream>>>(vu_bih, vu_bhh, vu_b, 512);
  pack_bias_kernel<<<2, 256, 0, stream>>>(nu_bih, nu_bhh, nu_b, 512);

  // persistent kernel: NB blocks, forced 1/CU by LDS footprint -> all co-resident
  int ns1 = (n_nodes + NB * 16 - 1) / (NB * 16);  // node-row subtiles (2 for 8000/250)
  if (ns1 <= 2) {
    persist_kernel<2><<<NB, 512, 0, stream>>>(
        row_ptr, col_idx, col_ptr, row_idx, values, true_W, true_b, false_W, false_b,
        packh, vu_b, nu_b, cm_b1, cm_b2, cm_b3, pm_b1, pm_b2, pm_b3,
        va1, va2, vs, h, bar, n_nodes, N, NB);
  } else {
    persist_kernel<3><<<NB, 512, 0, stream>>>(
        row_ptr, col_idx, col_ptr, row_idx, values, true_W, true_b, false_W, false_b,
        packh, vu_b, nu_b, cm_b1, cm_b2, cm_b3, pm_b1, pm_b2, pm_b3,
        va1, va2, vs, h, bar, n_nodes, N, NB);
  }

  vote_kernel<<<(n_vars + 31) / 32, 256, 0, stream>>>(h + (size_t)n_nodes * DIM, n_vars,
      vv_W1, vv_b1, vv_W2, vv_b2, vv_W3, vv_b3, (float*)d_out);
}